// Round 3
// baseline (588.402 us; speedup 1.0000x reference)
//
#include <hip/hip_runtime.h>

#define EPSF 1e-12f
constexpr int BB = 2;
constexpr int PP = 8192;
constexpr int VV = 4098;
constexpr int FF = 8192;

constexpr int TRI_F4 = 5;                // 5 x float4 per triangle record
constexpr int PTS_PER_BLOCK = 512;       // 2 points per thread, 256 threads
constexpr int NSLICES = 32;
constexpr int TRIS_PER_SLICE = FF / NSLICES;  // 256

// ---------------------------------------------------------------------------
// Kernel 1: gather triangle vertices + edge vectors, init minD.
// Record layout (float4):
//  R0 = (a.x, a.y, a.z, ab.x)
//  R1 = (b.x, b.y, b.z, ab.y)
//  R2 = (c.x, c.y, c.z, ab.z)
//  R3 = (ac.x, ac.y, ac.z, bc.x)
//  R4 = (bc.y, bc.z, 0, 0)
// ab=b-a, ac=c-a, bc=c-b computed as single fp32 subs (bit-matches numpy).
// ---------------------------------------------------------------------------
__global__ __launch_bounds__(256) void precompute_kernel(
    const float* __restrict__ verts, const int* __restrict__ faces,
    float4* __restrict__ tri, unsigned int* __restrict__ minD)
{
    int idx = blockIdx.x * 256 + threadIdx.x;
    if (idx < BB * PP) minD[idx] = 0x7F800000u;   // +inf
    if (idx >= BB * FF) return;

    int b = idx / FF;
    const float* vb = verts + (size_t)b * VV * 3;
    int i0 = faces[idx * 3 + 0];
    int i1 = faces[idx * 3 + 1];
    int i2 = faces[idx * 3 + 2];

    float ax = vb[i0*3+0], ay = vb[i0*3+1], az = vb[i0*3+2];
    float bx = vb[i1*3+0], by = vb[i1*3+1], bz = vb[i1*3+2];
    float cx = vb[i2*3+0], cy = vb[i2*3+1], cz = vb[i2*3+2];

    float abx = bx-ax, aby = by-ay, abz = bz-az;
    float acx = cx-ax, acy = cy-ay, acz = cz-az;
    float bcx = cx-bx, bcy = cy-by, bcz = cz-bz;

    float4* t = tri + (size_t)idx * TRI_F4;
    t[0] = make_float4(ax, ay, az, abx);
    t[1] = make_float4(bx, by, bz, aby);
    t[2] = make_float4(cx, cy, cz, abz);
    t[3] = make_float4(acx, acy, acz, bcx);
    t[4] = make_float4(bcy, bcz, 0.0f, 0.0f);
}

// ---------------------------------------------------------------------------
// Verbatim fp32 port of the reference closest_point_on_tri + |p-cp|^2.
// FMA contraction OFF and numpy evaluation order everywhere: the reference's
// region math is garbage-amplifying for sliver triangles (denom = va+vb+vc
// cancels to ~|n|^2 ~ 1e-6 from O(10) products), so the *rounding pattern*
// itself must be reproduced, not just the algebra.
// ---------------------------------------------------------------------------
__device__ __forceinline__ float tri_d2(
    float px, float py, float pz,
    float4 R0, float4 R1, float4 R2, float4 R3, float4 R4)
{
#pragma clang fp contract(off)
    float ax = R0.x, ay = R0.y, az = R0.z;
    float bx = R1.x, by = R1.y, bz = R1.z;
    float cx = R2.x, cy = R2.y, cz = R2.z;
    float abx = R0.w, aby = R1.w, abz = R2.w;
    float acx = R3.x, acy = R3.y, acz = R3.z;
    float bcx = R3.w, bcy = R4.x, bcz = R4.y;

    float apx = px - ax, apy = py - ay, apz = pz - az;
    float d1 = (abx*apx + aby*apy) + abz*apz;
    float d2 = (acx*apx + acy*apy) + acz*apz;
    float bpx = px - bx, bpy = py - by, bpz = pz - bz;
    float d3 = (abx*bpx + aby*bpy) + abz*bpz;
    float d4 = (acx*bpx + acy*bpy) + acz*bpz;
    float cqx = px - cx, cqy = py - cy, cqz = pz - cz;
    float d5 = (abx*cqx + aby*cqy) + abz*cqz;
    float d6 = (acx*cqx + acy*cqy) + acz*cqz;

    float va = d3*d6 - d5*d4;
    float vb = d5*d2 - d1*d6;
    float vc = d1*d4 - d3*d2;
    float u43 = d4 - d3;
    float u56 = d5 - d6;

    bool c1 = (d1 <= 0.0f) && (d2 <= 0.0f);
    bool c2 = (d3 >= 0.0f) && (d4 <= d3);
    bool c3 = (d6 >= 0.0f) && (d5 <= d6);
    bool c4 = (vc <= 0.0f) && (d1 >= 0.0f) && (d3 <= 0.0f);
    bool c5 = (vb <= 0.0f) && (d2 >= 0.0f) && (d6 <= 0.0f);
    bool c6 = (va <= 0.0f) && (u43 >= 0.0f) && (u56 >= 0.0f);

    // reference priority: c1 > c2 > c3 > c4 > c5 > c6 > interior
    int reg = c1 ? 0 : (c2 ? 1 : (c3 ? 2 : (c4 ? 3 : (c5 ? 4 : (c6 ? 5 : 6)))));

    float denom = fmaxf((va + vb) + vc, EPSF);
    float den1 = (reg == 3) ? fmaxf(d1 - d3, EPSF)
               : (reg == 5) ? fmaxf(u43 + u56, EPSF)
               : (reg == 6) ? denom : 1.0f;
    float num1 = (reg == 3) ? d1
               : (reg == 5) ? u43
               : (reg == 6) ? vb : 0.0f;
    float den2 = (reg == 4) ? fmaxf(d2 - d6, EPSF)
               : (reg == 6) ? denom : 1.0f;
    float num2 = (reg == 4) ? d2
               : (reg == 6) ? vc : 0.0f;
    float s = num1 / den1;   // v_ab / w_bc / v_in (or 0)
    float t = num2 / den2;   // w_ac / w_in        (or 0)

    bool useB = (reg == 1) || (reg == 5);
    bool useC = (reg == 2);
    float basex = useB ? bx : (useC ? cx : ax);
    float basey = useB ? by : (useC ? cy : ay);
    float basez = useB ? bz : (useC ? cz : az);
    bool e1bc = (reg == 5);
    float e1x = e1bc ? bcx : abx;
    float e1y = e1bc ? bcy : aby;
    float e1z = e1bc ? bcz : abz;

    // reference order: (base + e1*s) + ac*t ; adding exact zeros for the
    // vertex/edge branches reproduces the branch value (only ±0 can differ,
    // which cancels in the residual subtraction).
    float cpx = (basex + e1x*s) + acx*t;
    float cpy = (basey + e1y*s) + acy*t;
    float cpz = (basez + e1z*s) + acz*t;
    float rx = px - cpx, ry = py - cpy, rz = pz - cpz;
    return (rx*rx + ry*ry) + rz*rz;
}

// ---------------------------------------------------------------------------
// Kernel 2: brute-force min d^2, 2 points/thread, triangle slice per
// blockIdx.y, atomicMin(float-as-uint) at the end (valid: all d^2 >= 0).
// ---------------------------------------------------------------------------
__global__ __launch_bounds__(256) void dist_kernel(
    const float* __restrict__ pts, const float4* __restrict__ tri,
    unsigned int* __restrict__ minD)
{
    int tid   = threadIdx.x;
    int pg    = blockIdx.x;        // 0 .. 31
    int slice = blockIdx.y;        // 0 .. 31

    int b  = pg / (PP / PTS_PER_BLOCK);     // 16 point-groups per batch
    int p0 = pg * PTS_PER_BLOCK + tid;
    int p1 = p0 + 256;

    float px0 = pts[p0*3+0], py0 = pts[p0*3+1], pz0 = pts[p0*3+2];
    float px1 = pts[p1*3+0], py1 = pts[p1*3+1], pz1 = pts[p1*3+2];

    float m0 = __uint_as_float(0x7F800000u);
    float m1 = __uint_as_float(0x7F800000u);

    const float4* tb = tri + (size_t)(b * FF + slice * TRIS_PER_SLICE) * TRI_F4;

    for (int t = 0; t < TRIS_PER_SLICE; ++t) {
        float4 R0 = tb[t*TRI_F4+0];
        float4 R1 = tb[t*TRI_F4+1];
        float4 R2 = tb[t*TRI_F4+2];
        float4 R3 = tb[t*TRI_F4+3];
        float4 R4 = tb[t*TRI_F4+4];

        m0 = fminf(m0, tri_d2(px0, py0, pz0, R0, R1, R2, R3, R4));
        m1 = fminf(m1, tri_d2(px1, py1, pz1, R0, R1, R2, R3, R4));
    }

    atomicMin(&minD[p0], __float_as_uint(m0));
    atomicMin(&minD[p1], __float_as_uint(m1));
}

// ---------------------------------------------------------------------------
// Kernel 3: final reduction -> scalar loss
// ---------------------------------------------------------------------------
__global__ __launch_bounds__(256) void reduce_kernel(
    const unsigned int* __restrict__ minD, const float* __restrict__ verts,
    float* __restrict__ out)
{
    __shared__ float sh[256];
    int tid = threadIdx.x;
    float res = 0.0f;

    for (int b = 0; b < BB; ++b) {
        float s = 0.0f;
        for (int i = tid; i < PP; i += 256)
            s += __uint_as_float(minD[b * PP + i]);
        sh[tid] = s; __syncthreads();
        for (int off = 128; off > 0; off >>= 1) {
            if (tid < off) sh[tid] += sh[tid + off];
            __syncthreads();
        }
        float tot = sh[0]; __syncthreads();

        float ymin = 3.4e38f, ymax = -3.4e38f;
        for (int i = tid; i < VV; i += 256) {
            float y = verts[((size_t)b * VV + i) * 3 + 1];
            ymin = fminf(ymin, y); ymax = fmaxf(ymax, y);
        }
        sh[tid] = ymin; __syncthreads();
        for (int off = 128; off > 0; off >>= 1) {
            if (tid < off) sh[tid] = fminf(sh[tid], sh[tid + off]);
            __syncthreads();
        }
        float mn = sh[0]; __syncthreads();

        sh[tid] = ymax; __syncthreads();
        for (int off = 128; off > 0; off >>= 1) {
            if (tid < off) sh[tid] = fmaxf(sh[tid], sh[tid + off]);
            __syncthreads();
        }
        float mx = sh[0]; __syncthreads();

        res += sqrtf(tot) / (mx - mn);
    }

    if (tid == 0) out[0] = res * 0.5f;   // mean over B=2, LOSS_WEIGHT=1
}

// ---------------------------------------------------------------------------
extern "C" void kernel_launch(void* const* d_in, const int* in_sizes, int n_in,
                              void* d_out, int out_size, void* d_ws, size_t ws_size,
                              hipStream_t stream) {
    const float* pts   = (const float*)d_in[0];   // [B,P,3]
    const float* verts = (const float*)d_in[1];   // [B,V,3]
    const int*   faces = (const int*)d_in[2];     // [B,F,3]
    float* out = (float*)d_out;

    float4* tri = (float4*)d_ws;                               // B*F*5 float4
    size_t triBytes = (size_t)BB * FF * TRI_F4 * sizeof(float4);   // 1.3 MB
    unsigned int* minD = (unsigned int*)((char*)d_ws + triBytes);  // B*P uints

    precompute_kernel<<<(BB * FF + 255) / 256, 256, 0, stream>>>(verts, faces, tri, minD);

    dim3 grid(BB * PP / PTS_PER_BLOCK, NSLICES);
    dist_kernel<<<grid, 256, 0, stream>>>(pts, tri, minD);

    reduce_kernel<<<1, 256, 0, stream>>>(minD, verts, out);
}

// Round 4
// 349.322 us; speedup vs baseline: 1.6844x; 1.6844x over previous
//
#include <hip/hip_runtime.h>

#define EPSF 1e-12f
constexpr int BB = 2;
constexpr int PP = 8192;
constexpr int VV = 4098;
constexpr int FF = 8192;

constexpr int FAST_F4 = 7;               // fast-path record: 7 x float4
constexpr int SLOW_F4 = 5;               // verbatim-path record: 5 x float4
constexpr int PTS_PER_BLOCK = 512;       // 2 points per thread, 256 threads
constexpr int NSLICES = 32;
constexpr int TRIS_PER_SLICE = FF / NSLICES;  // 256

// ---------------------------------------------------------------------------
// Kernel 1: per-triangle records + classifier + minD init.
//
// SLOW record (bit-exact verbatim path, same as the proven R3 layout):
//  S0=(a,ab.x) S1=(b,ab.y) S2=(c,ab.z) S3=(ac,bc.x) S4=(bc.y,bc.z,0,0)
//
// FAST record (stable closed forms, FMA-friendly):
//  F0=(ab, ka1=ab.a) F1=(ac, ka2=ac.a) F2=(n=ab x ac, kan=n.a)
//  F3=(a, aa=|a|^2)  F4=(kb1=ab.b, kb2=ac.b, kc1=ab.c, kc2=ac.c)
//  F5=(1/|ab|^2, 1/|ac|^2, 1/|bc|^2, 1/|n|^2)
//  F6=(|ab|^2, |ac|^2, flag, 0)
//
// flag==fast iff sin^2(angle at a) = nn/(ab2*ac2) > 3e-2 and all edges^2>1e-4:
// then the reference's own barycentric quotients are accurate (no garbage
// amplification), so stable closed forms match ref to ~1e-4 absolute.
// ---------------------------------------------------------------------------
__global__ __launch_bounds__(256) void precompute_kernel(
    const float* __restrict__ verts, const int* __restrict__ faces,
    float4* __restrict__ fastrec, float4* __restrict__ slowrec,
    unsigned int* __restrict__ minD)
{
    int idx = blockIdx.x * 256 + threadIdx.x;
    if (idx < BB * PP) minD[idx] = 0x7F800000u;   // +inf
    if (idx >= BB * FF) return;

    int b = idx / FF;
    const float* vb = verts + (size_t)b * VV * 3;
    int i0 = faces[idx * 3 + 0];
    int i1 = faces[idx * 3 + 1];
    int i2 = faces[idx * 3 + 2];

    float ax = vb[i0*3+0], ay = vb[i0*3+1], az = vb[i0*3+2];
    float bx = vb[i1*3+0], by = vb[i1*3+1], bz = vb[i1*3+2];
    float cx = vb[i2*3+0], cy = vb[i2*3+1], cz = vb[i2*3+2];

    // plain fp32 subs: bit-match numpy (shared by both records)
    float abx = bx-ax, aby = by-ay, abz = bz-az;
    float acx = cx-ax, acy = cy-ay, acz = cz-az;
    float bcx = cx-bx, bcy = cy-by, bcz = cz-bz;

    // slow record
    {
        float4* t = slowrec + (size_t)idx * SLOW_F4;
        t[0] = make_float4(ax, ay, az, abx);
        t[1] = make_float4(bx, by, bz, aby);
        t[2] = make_float4(cx, cy, cz, abz);
        t[3] = make_float4(acx, acy, acz, bcx);
        t[4] = make_float4(bcy, bcz, 0.0f, 0.0f);
    }

    // fast record (rounding here is uncritical: only used on well-conditioned tris)
    float nx = aby*acz - abz*acy;
    float ny = abz*acx - abx*acz;
    float nz = abx*acy - aby*acx;

    float ka1 = abx*ax + aby*ay + abz*az;
    float ka2 = acx*ax + acy*ay + acz*az;
    float kb1 = abx*bx + aby*by + abz*bz;
    float kb2 = acx*bx + acy*by + acz*bz;
    float kc1 = abx*cx + aby*cy + abz*cz;
    float kc2 = acx*cx + acy*cy + acz*cz;
    float kan = nx*ax + ny*ay + nz*az;
    float aa  = ax*ax + ay*ay + az*az;

    float ab2 = abx*abx + aby*aby + abz*abz;
    float ac2 = acx*acx + acy*acy + acz*acz;
    float bc2 = bcx*bcx + bcy*bcy + bcz*bcz;
    float nn  = nx*nx + ny*ny + nz*nz;

    float inv_ab2 = 1.0f / fmaxf(ab2, EPSF);
    float inv_ac2 = 1.0f / fmaxf(ac2, EPSF);
    float inv_bc2 = 1.0f / fmaxf(bc2, EPSF);
    float inv_nn  = 1.0f / fmaxf(nn,  EPSF);

    bool fastok = (nn > 0.03f * (ab2 * ac2)) &&
                  (ab2 > 1e-4f) && (ac2 > 1e-4f) && (bc2 > 1e-4f);

    float4* f = fastrec + (size_t)idx * FAST_F4;
    f[0] = make_float4(abx, aby, abz, ka1);
    f[1] = make_float4(acx, acy, acz, ka2);
    f[2] = make_float4(nx,  ny,  nz,  kan);
    f[3] = make_float4(ax,  ay,  az,  aa);
    f[4] = make_float4(kb1, kb2, kc1, kc2);
    f[5] = make_float4(inv_ab2, inv_ac2, inv_bc2, inv_nn);
    f[6] = make_float4(ab2, ac2, fastok ? 1.0f : 0.0f, 0.0f);
}

// ---------------------------------------------------------------------------
// Verbatim fp32 port (bit-exact vs numpy) — used only for sliver/degenerate
// triangles where the reference's region math amplifies rounding garbage.
// Proven absmax==0.0 in R3.
// ---------------------------------------------------------------------------
__device__ __forceinline__ float tri_d2(
    float px, float py, float pz,
    float4 R0, float4 R1, float4 R2, float4 R3, float4 R4)
{
#pragma clang fp contract(off)
    float ax = R0.x, ay = R0.y, az = R0.z;
    float bx = R1.x, by = R1.y, bz = R1.z;
    float cx = R2.x, cy = R2.y, cz = R2.z;
    float abx = R0.w, aby = R1.w, abz = R2.w;
    float acx = R3.x, acy = R3.y, acz = R3.z;
    float bcx = R3.w, bcy = R4.x, bcz = R4.y;

    float apx = px - ax, apy = py - ay, apz = pz - az;
    float d1 = (abx*apx + aby*apy) + abz*apz;
    float d2 = (acx*apx + acy*apy) + acz*apz;
    float bpx = px - bx, bpy = py - by, bpz = pz - bz;
    float d3 = (abx*bpx + aby*bpy) + abz*bpz;
    float d4 = (acx*bpx + acy*bpy) + acz*bpz;
    float cqx = px - cx, cqy = py - cy, cqz = pz - cz;
    float d5 = (abx*cqx + aby*cqy) + abz*cqz;
    float d6 = (acx*cqx + acy*cqy) + acz*cqz;

    float va = d3*d6 - d5*d4;
    float vb = d5*d2 - d1*d6;
    float vc = d1*d4 - d3*d2;
    float u43 = d4 - d3;
    float u56 = d5 - d6;

    bool c1 = (d1 <= 0.0f) && (d2 <= 0.0f);
    bool c2 = (d3 >= 0.0f) && (d4 <= d3);
    bool c3 = (d6 >= 0.0f) && (d5 <= d6);
    bool c4 = (vc <= 0.0f) && (d1 >= 0.0f) && (d3 <= 0.0f);
    bool c5 = (vb <= 0.0f) && (d2 >= 0.0f) && (d6 <= 0.0f);
    bool c6 = (va <= 0.0f) && (u43 >= 0.0f) && (u56 >= 0.0f);

    int reg = c1 ? 0 : (c2 ? 1 : (c3 ? 2 : (c4 ? 3 : (c5 ? 4 : (c6 ? 5 : 6)))));

    float denom = fmaxf((va + vb) + vc, EPSF);
    float den1 = (reg == 3) ? fmaxf(d1 - d3, EPSF)
               : (reg == 5) ? fmaxf(u43 + u56, EPSF)
               : (reg == 6) ? denom : 1.0f;
    float num1 = (reg == 3) ? d1
               : (reg == 5) ? u43
               : (reg == 6) ? vb : 0.0f;
    float den2 = (reg == 4) ? fmaxf(d2 - d6, EPSF)
               : (reg == 6) ? denom : 1.0f;
    float num2 = (reg == 4) ? d2
               : (reg == 6) ? vc : 0.0f;
    float s = num1 / den1;
    float t = num2 / den2;

    bool useB = (reg == 1) || (reg == 5);
    bool useC = (reg == 2);
    float basex = useB ? bx : (useC ? cx : ax);
    float basey = useB ? by : (useC ? cy : ay);
    float basez = useB ? bz : (useC ? cz : az);
    bool e1bc = (reg == 5);
    float e1x = e1bc ? bcx : abx;
    float e1y = e1bc ? bcy : aby;
    float e1z = e1bc ? bcz : abz;

    float cpx = (basex + e1x*s) + acx*t;
    float cpy = (basey + e1y*s) + acy*t;
    float cpz = (basez + e1z*s) + acz*t;
    float rx = px - cpx, ry = py - cpy, rz = pz - cpz;
    return (rx*rx + ry*ry) + rz*rz;
}

// ---------------------------------------------------------------------------
// Fast path: stable closed-form region distances, no divides, FMA-contracted.
// Valid only for well-conditioned triangles (classifier in kernel 1).
// ---------------------------------------------------------------------------
__device__ __forceinline__ float fast_d2(
    float px, float py, float pz, float pp,
    float4 F0, float4 F1, float4 F2, float4 F3, float4 F4, float4 F5, float4 F6)
{
    float sab = fmaf(F0.x, px, fmaf(F0.y, py, F0.z * pz));
    float sac = fmaf(F1.x, px, fmaf(F1.y, py, F1.z * pz));
    float sn  = fmaf(F2.x, px, fmaf(F2.y, py, F2.z * pz));
    float adp = fmaf(F3.x, px, fmaf(F3.y, py, F3.z * pz));

    float d1 = sab - F0.w, d3 = sab - F4.x, d5 = sab - F4.z;
    float d2 = sac - F1.w, d4 = sac - F4.y, d6 = sac - F4.w;
    float tp = sn - F2.w;

    float ap2 = fmaf(-2.0f, adp, pp) + F3.w;     // |p-a|^2
    float bp2 = fmaf(-2.0f, d1, ap2) + F6.x;     // |p-b|^2
    float cp2 = fmaf(-2.0f, d2, ap2) + F6.y;     // |p-c|^2

    float va = fmaf(d3, d6, -(d5 * d4));
    float vb = fmaf(d5, d2, -(d1 * d6));
    float vc = fmaf(d1, d4, -(d3 * d2));
    float u43 = d4 - d3, u56 = d5 - d6;

    float dAB = fmaf(-(d1 * d1),   F5.x, ap2);
    float dAC = fmaf(-(d2 * d2),   F5.y, ap2);
    float dBC = fmaf(-(u43 * u43), F5.z, bp2);
    float dIN = (tp * tp) * F5.w;

    float r = dIN;
    r = (va <= 0.0f && u43 >= 0.0f && u56 >= 0.0f) ? dBC : r;
    r = (vb <= 0.0f && d2 >= 0.0f && d6 <= 0.0f)   ? dAC : r;
    r = (vc <= 0.0f && d1 >= 0.0f && d3 <= 0.0f)   ? dAB : r;
    r = (d6 >= 0.0f && d5 <= d6)                   ? cp2 : r;
    r = (d3 >= 0.0f && d4 <= d3)                   ? bp2 : r;
    r = (d1 <= 0.0f && d2 <= 0.0f)                 ? ap2 : r;
    // clamp: cancellation can give -1e-7; negative floats break uint atomicMin
    return fmaxf(r, 0.0f);
}

// ---------------------------------------------------------------------------
// Kernel 2: brute-force min d^2, 2 points/thread, wave-uniform per-triangle
// fast/slow branch (triangle data is uniform -> SGPRs, s_cbranch).
// ---------------------------------------------------------------------------
__global__ __launch_bounds__(256) void dist_kernel(
    const float* __restrict__ pts, const float4* __restrict__ fa,
    const float4* __restrict__ sa, unsigned int* __restrict__ minD)
{
    int tid   = threadIdx.x;
    int pg    = blockIdx.x;        // 0 .. 31
    int slice = blockIdx.y;        // 0 .. 31

    int b  = pg / (PP / PTS_PER_BLOCK);
    int p0 = pg * PTS_PER_BLOCK + tid;
    int p1 = p0 + 256;

    float px0 = pts[p0*3+0], py0 = pts[p0*3+1], pz0 = pts[p0*3+2];
    float px1 = pts[p1*3+0], py1 = pts[p1*3+1], pz1 = pts[p1*3+2];
    float pp0 = fmaf(px0, px0, fmaf(py0, py0, pz0 * pz0));
    float pp1 = fmaf(px1, px1, fmaf(py1, py1, pz1 * pz1));

    float m0 = __uint_as_float(0x7F800000u);
    float m1 = __uint_as_float(0x7F800000u);

    size_t tbase = (size_t)(b * FF + slice * TRIS_PER_SLICE);
    const float4* fb = fa + tbase * FAST_F4;
    const float4* sb = sa + tbase * SLOW_F4;

    for (int t = 0; t < TRIS_PER_SLICE; ++t) {
        float4 F6 = fb[t*FAST_F4+6];
        if (__builtin_amdgcn_readfirstlane(__float_as_int(F6.z))) {
            float4 F0 = fb[t*FAST_F4+0];
            float4 F1 = fb[t*FAST_F4+1];
            float4 F2 = fb[t*FAST_F4+2];
            float4 F3 = fb[t*FAST_F4+3];
            float4 F4 = fb[t*FAST_F4+4];
            float4 F5 = fb[t*FAST_F4+5];
            m0 = fminf(m0, fast_d2(px0, py0, pz0, pp0, F0, F1, F2, F3, F4, F5, F6));
            m1 = fminf(m1, fast_d2(px1, py1, pz1, pp1, F0, F1, F2, F3, F4, F5, F6));
        } else {
            float4 S0 = sb[t*SLOW_F4+0];
            float4 S1 = sb[t*SLOW_F4+1];
            float4 S2 = sb[t*SLOW_F4+2];
            float4 S3 = sb[t*SLOW_F4+3];
            float4 S4 = sb[t*SLOW_F4+4];
            m0 = fminf(m0, tri_d2(px0, py0, pz0, S0, S1, S2, S3, S4));
            m1 = fminf(m1, tri_d2(px1, py1, pz1, S0, S1, S2, S3, S4));
        }
    }

    atomicMin(&minD[p0], __float_as_uint(m0));
    atomicMin(&minD[p1], __float_as_uint(m1));
}

// ---------------------------------------------------------------------------
// Kernel 3: final reduction -> scalar loss
// ---------------------------------------------------------------------------
__global__ __launch_bounds__(256) void reduce_kernel(
    const unsigned int* __restrict__ minD, const float* __restrict__ verts,
    float* __restrict__ out)
{
    __shared__ float sh[256];
    int tid = threadIdx.x;
    float res = 0.0f;

    for (int b = 0; b < BB; ++b) {
        float s = 0.0f;
        for (int i = tid; i < PP; i += 256)
            s += __uint_as_float(minD[b * PP + i]);
        sh[tid] = s; __syncthreads();
        for (int off = 128; off > 0; off >>= 1) {
            if (tid < off) sh[tid] += sh[tid + off];
            __syncthreads();
        }
        float tot = sh[0]; __syncthreads();

        float ymin = 3.4e38f, ymax = -3.4e38f;
        for (int i = tid; i < VV; i += 256) {
            float y = verts[((size_t)b * VV + i) * 3 + 1];
            ymin = fminf(ymin, y); ymax = fmaxf(ymax, y);
        }
        sh[tid] = ymin; __syncthreads();
        for (int off = 128; off > 0; off >>= 1) {
            if (tid < off) sh[tid] = fminf(sh[tid], sh[tid + off]);
            __syncthreads();
        }
        float mn = sh[0]; __syncthreads();

        sh[tid] = ymax; __syncthreads();
        for (int off = 128; off > 0; off >>= 1) {
            if (tid < off) sh[tid] = fmaxf(sh[tid], sh[tid + off]);
            __syncthreads();
        }
        float mx = sh[0]; __syncthreads();

        res += sqrtf(tot) / (mx - mn);
    }

    if (tid == 0) out[0] = res * 0.5f;   // mean over B=2, LOSS_WEIGHT=1
}

// ---------------------------------------------------------------------------
extern "C" void kernel_launch(void* const* d_in, const int* in_sizes, int n_in,
                              void* d_out, int out_size, void* d_ws, size_t ws_size,
                              hipStream_t stream) {
    const float* pts   = (const float*)d_in[0];   // [B,P,3]
    const float* verts = (const float*)d_in[1];   // [B,V,3]
    const int*   faces = (const int*)d_in[2];     // [B,F,3]
    float* out = (float*)d_out;

    float4* fastrec = (float4*)d_ws;                                  // 1.75 MB
    size_t fastBytes = (size_t)BB * FF * FAST_F4 * sizeof(float4);
    float4* slowrec = (float4*)((char*)d_ws + fastBytes);             // 1.25 MB
    size_t slowBytes = (size_t)BB * FF * SLOW_F4 * sizeof(float4);
    unsigned int* minD = (unsigned int*)((char*)d_ws + fastBytes + slowBytes);

    precompute_kernel<<<(BB * FF + 255) / 256, 256, 0, stream>>>(
        verts, faces, fastrec, slowrec, minD);

    dim3 grid(BB * PP / PTS_PER_BLOCK, NSLICES);
    dist_kernel<<<grid, 256, 0, stream>>>(pts, fastrec, slowrec, minD);

    reduce_kernel<<<1, 256, 0, stream>>>(minD, verts, out);
}

// Round 5
// 252.821 us; speedup vs baseline: 2.3273x; 1.3817x over previous
//
#include <hip/hip_runtime.h>

#define EPSF 1e-12f
constexpr int BB = 2;
constexpr int PP = 8192;
constexpr int VV = 4098;
constexpr int FF = 8192;

constexpr int FAST_F4 = 7;               // fast record: 7 x float4
constexpr int SLOW_F4 = 5;               // verbatim record: 5 x float4
constexpr int PTS_PER_BLOCK = 1024;      // 4 points/thread x 256 threads
constexpr int NSLICES = 64;
constexpr int CHUNK_T = FF / NSLICES;    // 128 triangles/block (multiple of 64)

// ---------------------------------------------------------------------------
// Kernel 1: records + sliver bitmask (via __ballot, no atomics) + minD init.
//
// FAST record (min-of-candidates closed forms):
//  F0=(ab, ka1=ab.a) F1=(ac, ka2=ac.a) F2=(n, kan*) F3=(a, aa*=|a|^2)
//  F4=(kb1=ab.b, kb2=ac.b, kc1=ab.c, kc2=ac.c)
//  F5=(1/|ab|^2, 1/|ac|^2, 1/|bc|^2, 1/|n|^2)
//  F6=(|ab|^2, |ac|^2, |bc|^2, 0)
// Sliver poisoning: kan*=aa*=+inf => ap2=bp2=+inf and tp=-inf => all four
// candidates +inf (no 0*inf path: sA,sC,sB,inner products stay finite).
// SLOW record: verbatim vertices/edges (bit-exact path, proven R3).
// ---------------------------------------------------------------------------
__global__ __launch_bounds__(256) void precompute_kernel(
    const float* __restrict__ verts, const int* __restrict__ faces,
    float4* __restrict__ fastrec, float4* __restrict__ slowrec,
    unsigned long long* __restrict__ mask, unsigned int* __restrict__ minD)
{
    int idx = blockIdx.x * 256 + threadIdx.x;   // grid exactly covers BB*FF
    if (idx < BB * PP) minD[idx] = 0x7F800000u; // +inf
    if (idx >= BB * FF) return;

    int b = idx / FF;
    const float* vb = verts + (size_t)b * VV * 3;
    int i0 = faces[idx * 3 + 0];
    int i1 = faces[idx * 3 + 1];
    int i2 = faces[idx * 3 + 2];

    float ax = vb[i0*3+0], ay = vb[i0*3+1], az = vb[i0*3+2];
    float bx = vb[i1*3+0], by = vb[i1*3+1], bz = vb[i1*3+2];
    float cx = vb[i2*3+0], cy = vb[i2*3+1], cz = vb[i2*3+2];

    // plain fp32 subs: bit-match numpy (shared by both records)
    float abx = bx-ax, aby = by-ay, abz = bz-az;
    float acx = cx-ax, acy = cy-ay, acz = cz-az;
    float bcx = cx-bx, bcy = cy-by, bcz = cz-bz;

    {   // slow record (always written; read only for flagged tris)
        float4* t = slowrec + (size_t)idx * SLOW_F4;
        t[0] = make_float4(ax, ay, az, abx);
        t[1] = make_float4(bx, by, bz, aby);
        t[2] = make_float4(cx, cy, cz, abz);
        t[3] = make_float4(acx, acy, acz, bcx);
        t[4] = make_float4(bcy, bcz, 0.0f, 0.0f);
    }

    float nx = aby*acz - abz*acy;
    float ny = abz*acx - abx*acz;
    float nz = abx*acy - aby*acx;

    float ka1 = abx*ax + aby*ay + abz*az;
    float ka2 = acx*ax + acy*ay + acz*az;
    float kb1 = abx*bx + aby*by + abz*bz;
    float kb2 = acx*bx + acy*by + acz*bz;
    float kc1 = abx*cx + aby*cy + abz*cz;
    float kc2 = acx*cx + acy*cy + acz*cz;
    float kan = nx*ax + ny*ay + nz*az;
    float aa  = ax*ax + ay*ay + az*az;

    float ab2 = abx*abx + aby*aby + abz*abz;
    float ac2 = acx*acx + acy*acy + acz*acz;
    float bc2 = bcx*bcx + bcy*bcy + bcz*bcz;
    float nn  = nx*nx + ny*ny + nz*nz;

    float inv_ab2 = 1.0f / fmaxf(ab2, EPSF);
    float inv_ac2 = 1.0f / fmaxf(ac2, EPSF);
    float inv_bc2 = 1.0f / fmaxf(bc2, EPSF);
    float inv_nn  = 1.0f / fmaxf(nn,  EPSF);

    // sliver/degenerate classifier: sin^2(angle at a) <= 3e-2 or tiny edges
    bool slowtri = !((nn > 0.03f * (ab2 * ac2)) &&
                     (ab2 > 1e-4f) && (ac2 > 1e-4f) && (bc2 > 1e-4f));

    unsigned long long mb = __ballot(slowtri);
    if ((threadIdx.x & 63) == 0) mask[idx >> 6] = mb;

    float INF = __uint_as_float(0x7F800000u);
    float4* f = fastrec + (size_t)idx * FAST_F4;
    f[0] = make_float4(abx, aby, abz, ka1);
    f[1] = make_float4(acx, acy, acz, ka2);
    f[2] = make_float4(nx,  ny,  nz,  slowtri ? INF : kan);
    f[3] = make_float4(ax,  ay,  az,  slowtri ? INF : aa);
    f[4] = make_float4(kb1, kb2, kc1, kc2);
    f[5] = make_float4(inv_ab2, inv_ac2, inv_bc2, inv_nn);
    f[6] = make_float4(ab2, ac2, bc2, 0.0f);
}

// ---------------------------------------------------------------------------
// Verbatim fp32 port (bit-exact vs numpy) — slivers only. Proven in R3.
// ---------------------------------------------------------------------------
__device__ __forceinline__ float tri_d2(
    float px, float py, float pz,
    float4 R0, float4 R1, float4 R2, float4 R3, float4 R4)
{
#pragma clang fp contract(off)
    float ax = R0.x, ay = R0.y, az = R0.z;
    float bx = R1.x, by = R1.y, bz = R1.z;
    float cx = R2.x, cy = R2.y, cz = R2.z;
    float abx = R0.w, aby = R1.w, abz = R2.w;
    float acx = R3.x, acy = R3.y, acz = R3.z;
    float bcx = R3.w, bcy = R4.x, bcz = R4.y;

    float apx = px - ax, apy = py - ay, apz = pz - az;
    float d1 = (abx*apx + aby*apy) + abz*apz;
    float d2 = (acx*apx + acy*apy) + acz*apz;
    float bpx = px - bx, bpy = py - by, bpz = pz - bz;
    float d3 = (abx*bpx + aby*bpy) + abz*bpz;
    float d4 = (acx*bpx + acy*bpy) + acz*bpz;
    float cqx = px - cx, cqy = py - cy, cqz = pz - cz;
    float d5 = (abx*cqx + aby*cqy) + abz*cqz;
    float d6 = (acx*cqx + acy*cqy) + acz*cqz;

    float va = d3*d6 - d5*d4;
    float vb = d5*d2 - d1*d6;
    float vc = d1*d4 - d3*d2;
    float u43 = d4 - d3;
    float u56 = d5 - d6;

    bool c1 = (d1 <= 0.0f) && (d2 <= 0.0f);
    bool c2 = (d3 >= 0.0f) && (d4 <= d3);
    bool c3 = (d6 >= 0.0f) && (d5 <= d6);
    bool c4 = (vc <= 0.0f) && (d1 >= 0.0f) && (d3 <= 0.0f);
    bool c5 = (vb <= 0.0f) && (d2 >= 0.0f) && (d6 <= 0.0f);
    bool c6 = (va <= 0.0f) && (u43 >= 0.0f) && (u56 >= 0.0f);

    int reg = c1 ? 0 : (c2 ? 1 : (c3 ? 2 : (c4 ? 3 : (c5 ? 4 : (c6 ? 5 : 6)))));

    float denom = fmaxf((va + vb) + vc, EPSF);
    float den1 = (reg == 3) ? fmaxf(d1 - d3, EPSF)
               : (reg == 5) ? fmaxf(u43 + u56, EPSF)
               : (reg == 6) ? denom : 1.0f;
    float num1 = (reg == 3) ? d1
               : (reg == 5) ? u43
               : (reg == 6) ? vb : 0.0f;
    float den2 = (reg == 4) ? fmaxf(d2 - d6, EPSF)
               : (reg == 6) ? denom : 1.0f;
    float num2 = (reg == 4) ? d2
               : (reg == 6) ? vc : 0.0f;
    float s = num1 / den1;
    float t = num2 / den2;

    bool useB = (reg == 1) || (reg == 5);
    bool useC = (reg == 2);
    float basex = useB ? bx : (useC ? cx : ax);
    float basey = useB ? by : (useC ? cy : ay);
    float basez = useB ? bz : (useC ? cz : az);
    bool e1bc = (reg == 5);
    float e1x = e1bc ? bcx : abx;
    float e1y = e1bc ? bcy : aby;
    float e1z = e1bc ? bcz : abz;

    float cpx = (basex + e1x*s) + acx*t;
    float cpy = (basey + e1y*s) + acy*t;
    float cpz = (basez + e1z*s) + acz*t;
    float rx = px - cpx, ry = py - cpy, rz = pz - cpz;
    return (rx*rx + ry*ry) + rz*rz;
}

// ---------------------------------------------------------------------------
// Fast path: min of 4 candidates (3 clamped edges + gated interior).
// ~53 VALU/point, no divides, no cndmask cascade. Valid for well-conditioned
// triangles; poisoned records yield +inf for all candidates.
// ---------------------------------------------------------------------------
__device__ __forceinline__ float fast_d2(
    float px, float py, float pz, float pp,
    float4 F0, float4 F1, float4 F2, float4 F3, float4 F4, float4 F5, float4 F6)
{
    float sab = fmaf(F0.x, px, fmaf(F0.y, py, F0.z * pz));
    float sac = fmaf(F1.x, px, fmaf(F1.y, py, F1.z * pz));
    float sn  = fmaf(F2.x, px, fmaf(F2.y, py, F2.z * pz));
    float adp = fmaf(F3.x, px, fmaf(F3.y, py, F3.z * pz));

    float d1 = sab - F0.w, d2 = sac - F1.w;
    float d3 = sab - F4.x, d4 = sac - F4.y;
    float d5 = sab - F4.z, d6 = sac - F4.w;
    float tp = sn - F2.w;                        // -inf if poisoned

    float ap2 = fmaf(-2.0f, adp, pp) + F3.w;     // +inf if poisoned
    float bp2 = fmaf(-2.0f, d1, ap2) + F6.x;

    // clamped-edge candidates: |p - (base + s*e)|^2 = base2 - s*(2*dot - s*e2)
    float sA = fminf(fmaxf(d1 * F5.x, 0.0f), 1.0f);            // edge AB
    float dAB = fmaf(-sA, fmaf(-sA, F6.x, d1 + d1), ap2);
    float sC = fminf(fmaxf(d2 * F5.y, 0.0f), 1.0f);            // edge AC
    float dAC = fmaf(-sC, fmaf(-sC, F6.y, d2 + d2), ap2);
    float u43 = d4 - d3;
    float sB = fminf(fmaxf(u43 * F5.z, 0.0f), 1.0f);           // edge BC
    float dBC = fmaf(-sB, fmaf(-sB, F6.z, u43 + u43), bp2);

    // interior candidate, gated by barycentric sign test
    float va = fmaf(d3, d6, -(d5 * d4));
    float vb = fmaf(d5, d2, -(d1 * d6));
    float vc = fmaf(d1, d4, -(d3 * d2));
    bool inside = (va >= 0.0f) & (vb >= 0.0f) & (vc >= 0.0f);
    float dIN = (tp * tp) * F5.w;                // +inf if poisoned
    float dI = inside ? dIN : __uint_as_float(0x7F800000u);

    return fminf(fminf(dAB, dAC), fminf(dBC, dI));
}

// ---------------------------------------------------------------------------
// Kernel 2: 4 points/thread. Phase A: branchless fast loop over the chunk.
// Phase B: bitmask scan, exact (bit-exact) eval for flagged slivers.
// ---------------------------------------------------------------------------
__global__ __launch_bounds__(256) void dist_kernel(
    const float* __restrict__ pts, const float4* __restrict__ fa,
    const float4* __restrict__ sa, const unsigned long long* __restrict__ mask,
    unsigned int* __restrict__ minD)
{
    int tid   = threadIdx.x;
    int pg    = blockIdx.x;        // 0 .. 15
    int slice = blockIdx.y;        // 0 .. 63

    int b  = pg / (PP / PTS_PER_BLOCK);   // 8 point-groups per batch
    int p0 = pg * PTS_PER_BLOCK + tid;
    int p1 = p0 + 256, p2 = p0 + 512, p3 = p0 + 768;

    float px0 = pts[p0*3+0], py0 = pts[p0*3+1], pz0 = pts[p0*3+2];
    float px1 = pts[p1*3+0], py1 = pts[p1*3+1], pz1 = pts[p1*3+2];
    float px2 = pts[p2*3+0], py2 = pts[p2*3+1], pz2 = pts[p2*3+2];
    float px3 = pts[p3*3+0], py3 = pts[p3*3+1], pz3 = pts[p3*3+2];
    float pp0 = fmaf(px0, px0, fmaf(py0, py0, pz0 * pz0));
    float pp1 = fmaf(px1, px1, fmaf(py1, py1, pz1 * pz1));
    float pp2 = fmaf(px2, px2, fmaf(py2, py2, pz2 * pz2));
    float pp3 = fmaf(px3, px3, fmaf(py3, py3, pz3 * pz3));

    float m0 = __uint_as_float(0x7F800000u), m1 = m0, m2 = m0, m3 = m0;

    int t0 = b * FF + slice * CHUNK_T;
    const float4* fb = fa + (size_t)t0 * FAST_F4;

    for (int t = 0; t < CHUNK_T; ++t) {
        float4 F0 = fb[t*FAST_F4+0];
        float4 F1 = fb[t*FAST_F4+1];
        float4 F2 = fb[t*FAST_F4+2];
        float4 F3 = fb[t*FAST_F4+3];
        float4 F4 = fb[t*FAST_F4+4];
        float4 F5 = fb[t*FAST_F4+5];
        float4 F6 = fb[t*FAST_F4+6];
        m0 = fminf(m0, fast_d2(px0, py0, pz0, pp0, F0, F1, F2, F3, F4, F5, F6));
        m1 = fminf(m1, fast_d2(px1, py1, pz1, pp1, F0, F1, F2, F3, F4, F5, F6));
        m2 = fminf(m2, fast_d2(px2, py2, pz2, pp2, F0, F1, F2, F3, F4, F5, F6));
        m3 = fminf(m3, fast_d2(px3, py3, pz3, pp3, F0, F1, F2, F3, F4, F5, F6));
    }

    // Phase B: exact handling of flagged slivers in this chunk (~1 per block)
    for (int w = 0; w < CHUNK_T / 64; ++w) {
        unsigned long long bits = mask[(t0 >> 6) + w];
        while (bits) {
            int bit = __builtin_ctzll(bits);
            bits &= bits - 1;
            const float4* sb = sa + (size_t)(t0 + w*64 + bit) * SLOW_F4;
            float4 S0 = sb[0], S1 = sb[1], S2 = sb[2], S3 = sb[3], S4 = sb[4];
            m0 = fminf(m0, tri_d2(px0, py0, pz0, S0, S1, S2, S3, S4));
            m1 = fminf(m1, tri_d2(px1, py1, pz1, S0, S1, S2, S3, S4));
            m2 = fminf(m2, tri_d2(px2, py2, pz2, S0, S1, S2, S3, S4));
            m3 = fminf(m3, tri_d2(px3, py3, pz3, S0, S1, S2, S3, S4));
        }
    }

    // clamp once here (monotone: min(max(ri,0)) == max(min(ri),0));
    // negative floats would mis-order the uint atomicMin
    atomicMin(&minD[p0], __float_as_uint(fmaxf(m0, 0.0f)));
    atomicMin(&minD[p1], __float_as_uint(fmaxf(m1, 0.0f)));
    atomicMin(&minD[p2], __float_as_uint(fmaxf(m2, 0.0f)));
    atomicMin(&minD[p3], __float_as_uint(fmaxf(m3, 0.0f)));
}

// ---------------------------------------------------------------------------
// Kernel 3: final reduction -> scalar loss (1024 threads for latency)
// ---------------------------------------------------------------------------
__global__ __launch_bounds__(1024) void reduce_kernel(
    const unsigned int* __restrict__ minD, const float* __restrict__ verts,
    float* __restrict__ out)
{
    __shared__ float sh[1024];
    int tid = threadIdx.x;
    float res = 0.0f;

    for (int b = 0; b < BB; ++b) {
        float s = 0.0f;
        for (int i = tid; i < PP; i += 1024)
            s += __uint_as_float(minD[b * PP + i]);
        sh[tid] = s; __syncthreads();
        for (int off = 512; off > 0; off >>= 1) {
            if (tid < off) sh[tid] += sh[tid + off];
            __syncthreads();
        }
        float tot = sh[0]; __syncthreads();

        float ymin = 3.4e38f, ymax = -3.4e38f;
        for (int i = tid; i < VV; i += 1024) {
            float y = verts[((size_t)b * VV + i) * 3 + 1];
            ymin = fminf(ymin, y); ymax = fmaxf(ymax, y);
        }
        sh[tid] = ymin; __syncthreads();
        for (int off = 512; off > 0; off >>= 1) {
            if (tid < off) sh[tid] = fminf(sh[tid], sh[tid + off]);
            __syncthreads();
        }
        float mn = sh[0]; __syncthreads();

        sh[tid] = ymax; __syncthreads();
        for (int off = 512; off > 0; off >>= 1) {
            if (tid < off) sh[tid] = fmaxf(sh[tid], sh[tid + off]);
            __syncthreads();
        }
        float mx = sh[0]; __syncthreads();

        res += sqrtf(tot) / (mx - mn);
    }

    if (tid == 0) out[0] = res * 0.5f;   // mean over B=2, LOSS_WEIGHT=1
}

// ---------------------------------------------------------------------------
extern "C" void kernel_launch(void* const* d_in, const int* in_sizes, int n_in,
                              void* d_out, int out_size, void* d_ws, size_t ws_size,
                              hipStream_t stream) {
    const float* pts   = (const float*)d_in[0];   // [B,P,3]
    const float* verts = (const float*)d_in[1];   // [B,V,3]
    const int*   faces = (const int*)d_in[2];     // [B,F,3]
    float* out = (float*)d_out;

    char* w = (char*)d_ws;
    float4* fastrec = (float4*)w;                                   // 1.75 MB
    w += (size_t)BB * FF * FAST_F4 * sizeof(float4);
    float4* slowrec = (float4*)w;                                   // 1.25 MB
    w += (size_t)BB * FF * SLOW_F4 * sizeof(float4);
    unsigned long long* mask = (unsigned long long*)w;              // 2 KB
    w += (size_t)(BB * FF / 64) * sizeof(unsigned long long);
    unsigned int* minD = (unsigned int*)w;                          // 64 KB

    precompute_kernel<<<(BB * FF + 255) / 256, 256, 0, stream>>>(
        verts, faces, fastrec, slowrec, mask, minD);

    dim3 grid(BB * PP / PTS_PER_BLOCK, NSLICES);
    dist_kernel<<<grid, 256, 0, stream>>>(pts, fastrec, slowrec, mask, minD);

    reduce_kernel<<<1, 1024, 0, stream>>>(minD, verts, out);
}

// Round 6
// 236.629 us; speedup vs baseline: 2.4866x; 1.0684x over previous
//
#include <hip/hip_runtime.h>

#define EPSF 1e-12f
constexpr int BB = 2;
constexpr int PP = 8192;
constexpr int VV = 4098;
constexpr int FF = 8192;

constexpr int FAST_F4 = 7;               // fast record: 7 x float4
constexpr int SLOW_F4 = 5;               // verbatim record: 5 x float4
constexpr int PTS_PER_BLOCK = 2048;      // 8 points/thread x 256 threads
constexpr int NSLICES = 128;
constexpr int CHUNK_T = FF / NSLICES;    // 64 triangles/block = 1 mask word

typedef float f2 __attribute__((ext_vector_type(2)));

__device__ __forceinline__ f2 vfma(f2 a, f2 b, f2 c) {
#if __has_builtin(__builtin_elementwise_fma)
    return __builtin_elementwise_fma(a, b, c);
#else
    return (f2){fmaf(a.x, b.x, c.x), fmaf(a.y, b.y, c.y)};
#endif
}
__device__ __forceinline__ f2 vmin2(f2 a, f2 b) { return __builtin_elementwise_min(a, b); }
__device__ __forceinline__ f2 vmax2(f2 a, f2 b) { return __builtin_elementwise_max(a, b); }
__device__ __forceinline__ f2 bc(float s) { return (f2){s, s}; }

// ---------------------------------------------------------------------------
// Kernel 1: records + sliver bitmask + minD init + out zeroing.
// FAST record: F0=(ab,ka1) F1=(ac,ka2) F2=(n,kan*) F3=(a,aa*)
//              F4=(kb1,kb2,kc1,kc2) F5=(1/ab2,1/ac2,1/bc2,1/nn) F6=(ab2,ac2,bc2,0)
// Sliver poisoning: kan*=aa*=+inf => all four fast candidates +inf (no NaN path).
// SLOW record: verbatim vertices/edges for the bit-exact path (proven R3).
// ---------------------------------------------------------------------------
__global__ __launch_bounds__(256) void precompute_kernel(
    const float* __restrict__ verts, const int* __restrict__ faces,
    float4* __restrict__ fastrec, float4* __restrict__ slowrec,
    unsigned long long* __restrict__ mask, unsigned int* __restrict__ minD,
    float* __restrict__ out)
{
    int idx = blockIdx.x * 256 + threadIdx.x;   // grid exactly covers BB*FF
    if (idx == 0) out[0] = 0.0f;                // reduce_kernel atomicAdds into it
    if (idx < BB * PP) minD[idx] = 0x7F800000u; // +inf
    if (idx >= BB * FF) return;

    int b = idx / FF;
    const float* vb = verts + (size_t)b * VV * 3;
    int i0 = faces[idx * 3 + 0];
    int i1 = faces[idx * 3 + 1];
    int i2 = faces[idx * 3 + 2];

    float ax = vb[i0*3+0], ay = vb[i0*3+1], az = vb[i0*3+2];
    float bx = vb[i1*3+0], by = vb[i1*3+1], bz = vb[i1*3+2];
    float cx = vb[i2*3+0], cy = vb[i2*3+1], cz = vb[i2*3+2];

    // plain fp32 subs: bit-match numpy (shared by both records)
    float abx = bx-ax, aby = by-ay, abz = bz-az;
    float acx = cx-ax, acy = cy-ay, acz = cz-az;
    float bcx = cx-bx, bcy = cy-by, bcz = cz-bz;

    {   // slow record (read only for flagged tris)
        float4* t = slowrec + (size_t)idx * SLOW_F4;
        t[0] = make_float4(ax, ay, az, abx);
        t[1] = make_float4(bx, by, bz, aby);
        t[2] = make_float4(cx, cy, cz, abz);
        t[3] = make_float4(acx, acy, acz, bcx);
        t[4] = make_float4(bcy, bcz, 0.0f, 0.0f);
    }

    float nx = aby*acz - abz*acy;
    float ny = abz*acx - abx*acz;
    float nz = abx*acy - aby*acx;

    float ka1 = abx*ax + aby*ay + abz*az;
    float ka2 = acx*ax + acy*ay + acz*az;
    float kb1 = abx*bx + aby*by + abz*bz;
    float kb2 = acx*bx + acy*by + acz*bz;
    float kc1 = abx*cx + aby*cy + abz*cz;
    float kc2 = acx*cx + acy*cy + acz*cz;
    float kan = nx*ax + ny*ay + nz*az;
    float aa  = ax*ax + ay*ay + az*az;

    float ab2 = abx*abx + aby*aby + abz*abz;
    float ac2 = acx*acx + acy*acy + acz*acz;
    float bc2 = bcx*bcx + bcy*bcy + bcz*bcz;
    float nn  = nx*nx + ny*ny + nz*nz;

    float inv_ab2 = 1.0f / fmaxf(ab2, EPSF);
    float inv_ac2 = 1.0f / fmaxf(ac2, EPSF);
    float inv_bc2 = 1.0f / fmaxf(bc2, EPSF);
    float inv_nn  = 1.0f / fmaxf(nn,  EPSF);

    // sliver/degenerate classifier: sin^2(angle at a) <= 3e-2 or tiny edges
    bool slowtri = !((nn > 0.03f * (ab2 * ac2)) &&
                     (ab2 > 1e-4f) && (ac2 > 1e-4f) && (bc2 > 1e-4f));

    unsigned long long mb = __ballot(slowtri);
    if ((threadIdx.x & 63) == 0) mask[idx >> 6] = mb;

    float INF = __uint_as_float(0x7F800000u);
    float4* f = fastrec + (size_t)idx * FAST_F4;
    f[0] = make_float4(abx, aby, abz, ka1);
    f[1] = make_float4(acx, acy, acz, ka2);
    f[2] = make_float4(nx,  ny,  nz,  slowtri ? INF : kan);
    f[3] = make_float4(ax,  ay,  az,  slowtri ? INF : aa);
    f[4] = make_float4(kb1, kb2, kc1, kc2);
    f[5] = make_float4(inv_ab2, inv_ac2, inv_bc2, inv_nn);
    f[6] = make_float4(ab2, ac2, bc2, 0.0f);
}

// ---------------------------------------------------------------------------
// Verbatim fp32 port (bit-exact vs numpy) — slivers only. Proven in R3.
// ---------------------------------------------------------------------------
__device__ __forceinline__ float tri_d2(
    float px, float py, float pz,
    float4 R0, float4 R1, float4 R2, float4 R3, float4 R4)
{
#pragma clang fp contract(off)
    float ax = R0.x, ay = R0.y, az = R0.z;
    float bx = R1.x, by = R1.y, bz = R1.z;
    float cx = R2.x, cy = R2.y, cz = R2.z;
    float abx = R0.w, aby = R1.w, abz = R2.w;
    float acx = R3.x, acy = R3.y, acz = R3.z;
    float bcx = R3.w, bcy = R4.x, bcz = R4.y;

    float apx = px - ax, apy = py - ay, apz = pz - az;
    float d1 = (abx*apx + aby*apy) + abz*apz;
    float d2 = (acx*apx + acy*apy) + acz*apz;
    float bpx = px - bx, bpy = py - by, bpz = pz - bz;
    float d3 = (abx*bpx + aby*bpy) + abz*bpz;
    float d4 = (acx*bpx + acy*bpy) + acz*bpz;
    float cqx = px - cx, cqy = py - cy, cqz = pz - cz;
    float d5 = (abx*cqx + aby*cqy) + abz*cqz;
    float d6 = (acx*cqx + acy*cqy) + acz*cqz;

    float va = d3*d6 - d5*d4;
    float vb = d5*d2 - d1*d6;
    float vc = d1*d4 - d3*d2;
    float u43 = d4 - d3;
    float u56 = d5 - d6;

    bool c1 = (d1 <= 0.0f) && (d2 <= 0.0f);
    bool c2 = (d3 >= 0.0f) && (d4 <= d3);
    bool c3 = (d6 >= 0.0f) && (d5 <= d6);
    bool c4 = (vc <= 0.0f) && (d1 >= 0.0f) && (d3 <= 0.0f);
    bool c5 = (vb <= 0.0f) && (d2 >= 0.0f) && (d6 <= 0.0f);
    bool c6 = (va <= 0.0f) && (u43 >= 0.0f) && (u56 >= 0.0f);

    int reg = c1 ? 0 : (c2 ? 1 : (c3 ? 2 : (c4 ? 3 : (c5 ? 4 : (c6 ? 5 : 6)))));

    float denom = fmaxf((va + vb) + vc, EPSF);
    float den1 = (reg == 3) ? fmaxf(d1 - d3, EPSF)
               : (reg == 5) ? fmaxf(u43 + u56, EPSF)
               : (reg == 6) ? denom : 1.0f;
    float num1 = (reg == 3) ? d1
               : (reg == 5) ? u43
               : (reg == 6) ? vb : 0.0f;
    float den2 = (reg == 4) ? fmaxf(d2 - d6, EPSF)
               : (reg == 6) ? denom : 1.0f;
    float num2 = (reg == 4) ? d2
               : (reg == 6) ? vc : 0.0f;
    float s = num1 / den1;
    float t = num2 / den2;

    bool useB = (reg == 1) || (reg == 5);
    bool useC = (reg == 2);
    float basex = useB ? bx : (useC ? cx : ax);
    float basey = useB ? by : (useC ? cy : ay);
    float basez = useB ? bz : (useC ? cz : az);
    bool e1bc = (reg == 5);
    float e1x = e1bc ? bcx : abx;
    float e1y = e1bc ? bcy : aby;
    float e1z = e1bc ? bcz : abz;

    float cpx = (basex + e1x*s) + acx*t;
    float cpy = (basey + e1y*s) + acy*t;
    float cpz = (basez + e1z*s) + acz*t;
    float rx = px - cpx, ry = py - cpy, rz = pz - cpz;
    return (rx*rx + ry*ry) + rz*rz;
}

// ---------------------------------------------------------------------------
// Packed fast path: 2 points per call on f2 lanes. fma/mul/add lower to
// v_pk_*_f32 (VOP3P, 2 fp32 ops/lane/instr); cmp/select/min scalarize.
// Same formulas as R5 (min of 3 clamped edges + gated interior).
// ---------------------------------------------------------------------------
__device__ __forceinline__ f2 fast_d2_pk(
    f2 px, f2 py, f2 pz, f2 pp,
    float4 F0, float4 F1, float4 F2, float4 F3, float4 F4, float4 F5, float4 F6)
{
    const float INF = __uint_as_float(0x7F800000u);

    f2 sab = vfma(bc(F0.x), px, vfma(bc(F0.y), py, bc(F0.z) * pz));
    f2 sac = vfma(bc(F1.x), px, vfma(bc(F1.y), py, bc(F1.z) * pz));
    f2 sn  = vfma(bc(F2.x), px, vfma(bc(F2.y), py, bc(F2.z) * pz));
    f2 adp = vfma(bc(F3.x), px, vfma(bc(F3.y), py, bc(F3.z) * pz));

    f2 d1 = sab - bc(F0.w), d2 = sac - bc(F1.w);
    f2 d3 = sab - bc(F4.x), d4 = sac - bc(F4.y);
    f2 d5 = sab - bc(F4.z), d6 = sac - bc(F4.w);
    f2 tp = sn - bc(F2.w);                       // -inf if poisoned

    f2 ap2 = vfma(bc(-2.0f), adp, pp) + bc(F3.w);  // +inf if poisoned
    f2 bp2 = vfma(bc(-2.0f), d1, ap2) + bc(F6.x);

    f2 sA = vmin2(vmax2(d1 * bc(F5.x), bc(0.0f)), bc(1.0f));       // edge AB
    f2 dAB = vfma(-sA, vfma(-sA, bc(F6.x), d1 + d1), ap2);
    f2 sC = vmin2(vmax2(d2 * bc(F5.y), bc(0.0f)), bc(1.0f));       // edge AC
    f2 dAC = vfma(-sC, vfma(-sC, bc(F6.y), d2 + d2), ap2);
    f2 u43 = d4 - d3;
    f2 sB = vmin2(vmax2(u43 * bc(F5.z), bc(0.0f)), bc(1.0f));      // edge BC
    f2 dBC = vfma(-sB, vfma(-sB, bc(F6.z), u43 + u43), bp2);

    f2 va = vfma(d3, d6, -(d5 * d4));
    f2 vb = vfma(d5, d2, -(d1 * d6));
    f2 vc = vfma(d1, d4, -(d3 * d2));
    f2 dIN = (tp * tp) * bc(F5.w);               // +inf if poisoned

    f2 dI;
    dI.x = (va.x >= 0.0f && vb.x >= 0.0f && vc.x >= 0.0f) ? dIN.x : INF;
    dI.y = (va.y >= 0.0f && vb.y >= 0.0f && vc.y >= 0.0f) ? dIN.y : INF;

    return vmin2(vmin2(dAB, dAC), vmin2(dBC, dI));
}

// ---------------------------------------------------------------------------
// Kernel 2: 8 points/thread as 4 packed pairs. Phase A: branchless pk loop.
// Phase B: bitmask scan, bit-exact eval for flagged slivers (~1/block).
// ---------------------------------------------------------------------------
__global__ __launch_bounds__(256) void dist_kernel(
    const float* __restrict__ pts, const float4* __restrict__ fa,
    const float4* __restrict__ sa, const unsigned long long* __restrict__ mask,
    unsigned int* __restrict__ minD)
{
    int tid   = threadIdx.x;
    int pg    = blockIdx.x;        // 0 .. 7
    int slice = blockIdx.y;        // 0 .. 127

    int b  = pg / (PP / PTS_PER_BLOCK);   // 4 point-groups per batch
    int p0 = pg * PTS_PER_BLOCK + tid;

    f2 px[4], py[4], pz[4], pp[4], m[4];
    int pidx[8];
#pragma unroll
    for (int k = 0; k < 4; ++k) {
        int pa = p0 + (2*k)   * 256;
        int pb = p0 + (2*k+1) * 256;
        pidx[2*k] = pa; pidx[2*k+1] = pb;
        px[k] = (f2){pts[pa*3+0], pts[pb*3+0]};
        py[k] = (f2){pts[pa*3+1], pts[pb*3+1]};
        pz[k] = (f2){pts[pa*3+2], pts[pb*3+2]};
        pp[k] = vfma(px[k], px[k], vfma(py[k], py[k], pz[k] * pz[k]));
        m[k] = bc(__uint_as_float(0x7F800000u));
    }

    int t0 = b * FF + slice * CHUNK_T;
    const float4* fb = fa + (size_t)t0 * FAST_F4;

    for (int t = 0; t < CHUNK_T; ++t) {
        float4 F0 = fb[t*FAST_F4+0];
        float4 F1 = fb[t*FAST_F4+1];
        float4 F2 = fb[t*FAST_F4+2];
        float4 F3 = fb[t*FAST_F4+3];
        float4 F4 = fb[t*FAST_F4+4];
        float4 F5 = fb[t*FAST_F4+5];
        float4 F6 = fb[t*FAST_F4+6];
#pragma unroll
        for (int k = 0; k < 4; ++k)
            m[k] = vmin2(m[k], fast_d2_pk(px[k], py[k], pz[k], pp[k],
                                          F0, F1, F2, F3, F4, F5, F6));
    }

    // Phase B: exact handling of flagged slivers in this chunk (CHUNK_T==64
    // => exactly one mask word; wave-uniform scan)
    unsigned long long bits = mask[t0 >> 6];
    while (bits) {
        int bit = __builtin_ctzll(bits);
        bits &= bits - 1;
        const float4* sb = sa + (size_t)(t0 + bit) * SLOW_F4;
        float4 S0 = sb[0], S1 = sb[1], S2 = sb[2], S3 = sb[3], S4 = sb[4];
#pragma unroll
        for (int k = 0; k < 4; ++k) {
            m[k].x = fminf(m[k].x, tri_d2(px[k].x, py[k].x, pz[k].x, S0, S1, S2, S3, S4));
            m[k].y = fminf(m[k].y, tri_d2(px[k].y, py[k].y, pz[k].y, S0, S1, S2, S3, S4));
        }
    }

    // clamp (monotone) then float-as-uint atomicMin (valid: values >= 0)
#pragma unroll
    for (int k = 0; k < 4; ++k) {
        atomicMin(&minD[pidx[2*k]],   __float_as_uint(fmaxf(m[k].x, 0.0f)));
        atomicMin(&minD[pidx[2*k+1]], __float_as_uint(fmaxf(m[k].y, 0.0f)));
    }
}

// ---------------------------------------------------------------------------
// Kernel 3: per-batch reduction (2 blocks), shuffle + LDS, atomicAdd into out
// (out zeroed by precompute_kernel earlier in the stream).
// ---------------------------------------------------------------------------
__global__ __launch_bounds__(256) void reduce_kernel(
    const unsigned int* __restrict__ minD, const float* __restrict__ verts,
    float* __restrict__ out)
{
    int b = blockIdx.x;
    int tid = threadIdx.x;

    float s = 0.0f;
    for (int i = tid; i < PP; i += 256)
        s += __uint_as_float(minD[b * PP + i]);

    float ymin = 3.4e38f, ymax = -3.4e38f;
    for (int i = tid; i < VV; i += 256) {
        float y = verts[((size_t)b * VV + i) * 3 + 1];
        ymin = fminf(ymin, y); ymax = fmaxf(ymax, y);
    }

    for (int off = 32; off > 0; off >>= 1) {
        s += __shfl_down(s, off);
        ymin = fminf(ymin, __shfl_down(ymin, off));
        ymax = fmaxf(ymax, __shfl_down(ymax, off));
    }

    __shared__ float shs[4], shmn[4], shmx[4];
    if ((tid & 63) == 0) {
        int w = tid >> 6;
        shs[w] = s; shmn[w] = ymin; shmx[w] = ymax;
    }
    __syncthreads();
    if (tid == 0) {
        float tot = shs[0], mn = shmn[0], mx = shmx[0];
        for (int w = 1; w < 4; ++w) {
            tot += shs[w];
            mn = fminf(mn, shmn[w]);
            mx = fmaxf(mx, shmx[w]);
        }
        atomicAdd(out, 0.5f * sqrtf(tot) / (mx - mn));  // mean over B=2
    }
}

// ---------------------------------------------------------------------------
extern "C" void kernel_launch(void* const* d_in, const int* in_sizes, int n_in,
                              void* d_out, int out_size, void* d_ws, size_t ws_size,
                              hipStream_t stream) {
    const float* pts   = (const float*)d_in[0];   // [B,P,3]
    const float* verts = (const float*)d_in[1];   // [B,V,3]
    const int*   faces = (const int*)d_in[2];     // [B,F,3]
    float* out = (float*)d_out;

    char* w = (char*)d_ws;
    float4* fastrec = (float4*)w;                                   // 1.75 MB
    w += (size_t)BB * FF * FAST_F4 * sizeof(float4);
    float4* slowrec = (float4*)w;                                   // 1.25 MB
    w += (size_t)BB * FF * SLOW_F4 * sizeof(float4);
    unsigned long long* mask = (unsigned long long*)w;              // 2 KB
    w += (size_t)(BB * FF / 64) * sizeof(unsigned long long);
    unsigned int* minD = (unsigned int*)w;                          // 64 KB

    precompute_kernel<<<(BB * FF + 255) / 256, 256, 0, stream>>>(
        verts, faces, fastrec, slowrec, mask, minD, out);

    dim3 grid(BB * PP / PTS_PER_BLOCK, NSLICES);
    dist_kernel<<<grid, 256, 0, stream>>>(pts, fastrec, slowrec, mask, minD);

    reduce_kernel<<<BB, 256, 0, stream>>>(minD, verts, out);
}

// Round 7
// 217.009 us; speedup vs baseline: 2.7114x; 1.0904x over previous
//
#include <hip/hip_runtime.h>

#define EPSF 1e-12f
constexpr int BB = 2;
constexpr int PP = 8192;
constexpr int VV = 4098;
constexpr int FF = 8192;

constexpr int FAST_F4 = 6;               // fast record: 6 x float4
constexpr int SLOW_F4 = 5;               // verbatim record: 5 x float4
constexpr int PTS_PER_BLOCK = 2048;      // 8 points/thread x 256 threads
constexpr int NSLICES = 256;
constexpr int CHUNK_T = FF / NSLICES;    // 32 triangles/block = half mask word

typedef float f2 __attribute__((ext_vector_type(2)));

__device__ __forceinline__ f2 vfma(f2 a, f2 b, f2 c) {
#if __has_builtin(__builtin_elementwise_fma)
    return __builtin_elementwise_fma(a, b, c);
#else
    return (f2){fmaf(a.x, b.x, c.x), fmaf(a.y, b.y, c.y)};
#endif
}
__device__ __forceinline__ f2 vmin2(f2 a, f2 b) { return __builtin_elementwise_min(a, b); }
__device__ __forceinline__ f2 vmax2(f2 a, f2 b) { return __builtin_elementwise_max(a, b); }
__device__ __forceinline__ f2 bc(float s) { return (f2){s, s}; }

// ---------------------------------------------------------------------------
// Kernel 1: records + sliver bitmask + minD init + out zeroing.
// FAST record (24 consts): F0=(ab,ka1) F1=(ac,ka2) F2=(n,kan*) F3=(a,aa*)
//   F4=(ab2, ac2, abac, bc2)  F5=(1/ab2, 1/ac2, 1/bc2, 1/nn)
// Derived in-loop: d3=d1-ab2, d4=d2-abac, d5=d1-abac, d6=d2-ac2.
// Sliver poisoning: kan*=aa*=+inf => all four fast candidates +inf (no NaN).
// SLOW record: verbatim vertices/edges for the bit-exact path (proven R3).
// ---------------------------------------------------------------------------
__global__ __launch_bounds__(256) void precompute_kernel(
    const float* __restrict__ verts, const int* __restrict__ faces,
    float4* __restrict__ fastrec, float4* __restrict__ slowrec,
    unsigned long long* __restrict__ mask, unsigned int* __restrict__ minD,
    float* __restrict__ out)
{
    int idx = blockIdx.x * 256 + threadIdx.x;   // grid exactly covers BB*FF
    if (idx == 0) out[0] = 0.0f;                // reduce_kernel atomicAdds into it
    if (idx < BB * PP) minD[idx] = 0x7F800000u; // +inf
    if (idx >= BB * FF) return;

    int b = idx / FF;
    const float* vb = verts + (size_t)b * VV * 3;
    int i0 = faces[idx * 3 + 0];
    int i1 = faces[idx * 3 + 1];
    int i2 = faces[idx * 3 + 2];

    float ax = vb[i0*3+0], ay = vb[i0*3+1], az = vb[i0*3+2];
    float bx = vb[i1*3+0], by = vb[i1*3+1], bz = vb[i1*3+2];
    float cx = vb[i2*3+0], cy = vb[i2*3+1], cz = vb[i2*3+2];

    // plain fp32 subs: bit-match numpy (shared by both records)
    float abx = bx-ax, aby = by-ay, abz = bz-az;
    float acx = cx-ax, acy = cy-ay, acz = cz-az;
    float bcx = cx-bx, bcy = cy-by, bcz = cz-bz;

    {   // slow record (read only for flagged tris)
        float4* t = slowrec + (size_t)idx * SLOW_F4;
        t[0] = make_float4(ax, ay, az, abx);
        t[1] = make_float4(bx, by, bz, aby);
        t[2] = make_float4(cx, cy, cz, abz);
        t[3] = make_float4(acx, acy, acz, bcx);
        t[4] = make_float4(bcy, bcz, 0.0f, 0.0f);
    }

    float nx = aby*acz - abz*acy;
    float ny = abz*acx - abx*acz;
    float nz = abx*acy - aby*acx;

    float ka1  = abx*ax + aby*ay + abz*az;
    float ka2  = acx*ax + acy*ay + acz*az;
    float kan  = nx*ax + ny*ay + nz*az;
    float aa   = ax*ax + ay*ay + az*az;
    float abac = abx*acx + aby*acy + abz*acz;

    float ab2 = abx*abx + aby*aby + abz*abz;
    float ac2 = acx*acx + acy*acy + acz*acz;
    float bc2 = bcx*bcx + bcy*bcy + bcz*bcz;
    float nn  = nx*nx + ny*ny + nz*nz;

    float inv_ab2 = 1.0f / fmaxf(ab2, EPSF);
    float inv_ac2 = 1.0f / fmaxf(ac2, EPSF);
    float inv_bc2 = 1.0f / fmaxf(bc2, EPSF);
    float inv_nn  = 1.0f / fmaxf(nn,  EPSF);

    // sliver/degenerate classifier: sin^2(angle at a) <= 3e-2 or tiny edges
    bool slowtri = !((nn > 0.03f * (ab2 * ac2)) &&
                     (ab2 > 1e-4f) && (ac2 > 1e-4f) && (bc2 > 1e-4f));

    unsigned long long mb = __ballot(slowtri);
    if ((threadIdx.x & 63) == 0) mask[idx >> 6] = mb;

    float INF = __uint_as_float(0x7F800000u);
    float4* f = fastrec + (size_t)idx * FAST_F4;
    f[0] = make_float4(abx, aby, abz, ka1);
    f[1] = make_float4(acx, acy, acz, ka2);
    f[2] = make_float4(nx,  ny,  nz,  slowtri ? INF : kan);
    f[3] = make_float4(ax,  ay,  az,  slowtri ? INF : aa);
    f[4] = make_float4(ab2, ac2, abac, bc2);
    f[5] = make_float4(inv_ab2, inv_ac2, inv_bc2, inv_nn);
}

// ---------------------------------------------------------------------------
// Verbatim fp32 port (bit-exact vs numpy) — slivers only. Proven in R3.
// ---------------------------------------------------------------------------
__device__ __forceinline__ float tri_d2(
    float px, float py, float pz,
    float4 R0, float4 R1, float4 R2, float4 R3, float4 R4)
{
#pragma clang fp contract(off)
    float ax = R0.x, ay = R0.y, az = R0.z;
    float bx = R1.x, by = R1.y, bz = R1.z;
    float cx = R2.x, cy = R2.y, cz = R2.z;
    float abx = R0.w, aby = R1.w, abz = R2.w;
    float acx = R3.x, acy = R3.y, acz = R3.z;
    float bcx = R3.w, bcy = R4.x, bcz = R4.y;

    float apx = px - ax, apy = py - ay, apz = pz - az;
    float d1 = (abx*apx + aby*apy) + abz*apz;
    float d2 = (acx*apx + acy*apy) + acz*apz;
    float bpx = px - bx, bpy = py - by, bpz = pz - bz;
    float d3 = (abx*bpx + aby*bpy) + abz*bpz;
    float d4 = (acx*bpx + acy*bpy) + acz*bpz;
    float cqx = px - cx, cqy = py - cy, cqz = pz - cz;
    float d5 = (abx*cqx + aby*cqy) + abz*cqz;
    float d6 = (acx*cqx + acy*cqy) + acz*cqz;

    float va = d3*d6 - d5*d4;
    float vb = d5*d2 - d1*d6;
    float vc = d1*d4 - d3*d2;
    float u43 = d4 - d3;
    float u56 = d5 - d6;

    bool c1 = (d1 <= 0.0f) && (d2 <= 0.0f);
    bool c2 = (d3 >= 0.0f) && (d4 <= d3);
    bool c3 = (d6 >= 0.0f) && (d5 <= d6);
    bool c4 = (vc <= 0.0f) && (d1 >= 0.0f) && (d3 <= 0.0f);
    bool c5 = (vb <= 0.0f) && (d2 >= 0.0f) && (d6 <= 0.0f);
    bool c6 = (va <= 0.0f) && (u43 >= 0.0f) && (u56 >= 0.0f);

    int reg = c1 ? 0 : (c2 ? 1 : (c3 ? 2 : (c4 ? 3 : (c5 ? 4 : (c6 ? 5 : 6)))));

    float denom = fmaxf((va + vb) + vc, EPSF);
    float den1 = (reg == 3) ? fmaxf(d1 - d3, EPSF)
               : (reg == 5) ? fmaxf(u43 + u56, EPSF)
               : (reg == 6) ? denom : 1.0f;
    float num1 = (reg == 3) ? d1
               : (reg == 5) ? u43
               : (reg == 6) ? vb : 0.0f;
    float den2 = (reg == 4) ? fmaxf(d2 - d6, EPSF)
               : (reg == 6) ? denom : 1.0f;
    float num2 = (reg == 4) ? d2
               : (reg == 6) ? vc : 0.0f;
    float s = num1 / den1;
    float t = num2 / den2;

    bool useB = (reg == 1) || (reg == 5);
    bool useC = (reg == 2);
    float basex = useB ? bx : (useC ? cx : ax);
    float basey = useB ? by : (useC ? cy : ay);
    float basez = useB ? bz : (useC ? cz : az);
    bool e1bc = (reg == 5);
    float e1x = e1bc ? bcx : abx;
    float e1y = e1bc ? bcy : aby;
    float e1z = e1bc ? bcz : abz;

    float cpx = (basex + e1x*s) + acx*t;
    float cpy = (basey + e1y*s) + acy*t;
    float cpz = (basez + e1z*s) + acz*t;
    float rx = px - cpx, ry = py - cpy, rz = pz - cpz;
    return (rx*rx + ry*ry) + rz*rz;
}

// ---------------------------------------------------------------------------
// Packed fast path: 2 points per call. min of 3 clamped edges + gated
// interior; d3..d6 derived from d1,d2 via triangle constants.
// ---------------------------------------------------------------------------
__device__ __forceinline__ f2 fast_d2_pk(
    f2 px, f2 py, f2 pz, f2 pp,
    float4 F0, float4 F1, float4 F2, float4 F3, float4 F4, float4 F5)
{
    const float INF = __uint_as_float(0x7F800000u);

    f2 sab = vfma(bc(F0.x), px, vfma(bc(F0.y), py, bc(F0.z) * pz));
    f2 sac = vfma(bc(F1.x), px, vfma(bc(F1.y), py, bc(F1.z) * pz));
    f2 sn  = vfma(bc(F2.x), px, vfma(bc(F2.y), py, bc(F2.z) * pz));
    f2 adp = vfma(bc(F3.x), px, vfma(bc(F3.y), py, bc(F3.z) * pz));

    f2 d1 = sab - bc(F0.w), d2 = sac - bc(F1.w);
    f2 d3 = d1 - bc(F4.x);                       // - |ab|^2
    f2 d4 = d2 - bc(F4.z);                       // - ab.ac
    f2 d5 = d1 - bc(F4.z);                       // - ab.ac
    f2 d6 = d2 - bc(F4.y);                       // - |ac|^2
    f2 tp = sn - bc(F2.w);                       // -inf if poisoned

    f2 ap2 = vfma(bc(-2.0f), adp, pp) + bc(F3.w);  // +inf if poisoned
    f2 bp2 = vfma(bc(-2.0f), d1, ap2) + bc(F4.x);

    f2 sA = vmin2(vmax2(d1 * bc(F5.x), bc(0.0f)), bc(1.0f));       // edge AB
    f2 dAB = vfma(-sA, vfma(-sA, bc(F4.x), d1 + d1), ap2);
    f2 sC = vmin2(vmax2(d2 * bc(F5.y), bc(0.0f)), bc(1.0f));       // edge AC
    f2 dAC = vfma(-sC, vfma(-sC, bc(F4.y), d2 + d2), ap2);
    f2 u43 = d4 - d3;
    f2 sB = vmin2(vmax2(u43 * bc(F5.z), bc(0.0f)), bc(1.0f));      // edge BC
    f2 dBC = vfma(-sB, vfma(-sB, bc(F4.w), u43 + u43), bp2);

    f2 va = vfma(d3, d6, -(d5 * d4));
    f2 vb = vfma(d5, d2, -(d1 * d6));
    f2 vc = vfma(d1, d4, -(d3 * d2));
    f2 mv = vmin2(vmin2(va, vb), vc);
    f2 dIN = (tp * tp) * bc(F5.w);               // +inf if poisoned

    f2 dI;
    dI.x = (mv.x >= 0.0f) ? dIN.x : INF;
    dI.y = (mv.y >= 0.0f) ? dIN.y : INF;

    return vmin2(vmin2(dAB, dAC), vmin2(dBC, dI));
}

// ---------------------------------------------------------------------------
// Kernel 2: 8 points/thread as 4 packed pairs, 32 triangles/block.
// ---------------------------------------------------------------------------
__global__ __launch_bounds__(256) void dist_kernel(
    const float* __restrict__ pts, const float4* __restrict__ fa,
    const float4* __restrict__ sa, const unsigned long long* __restrict__ mask,
    unsigned int* __restrict__ minD)
{
    int tid   = threadIdx.x;
    int pg    = blockIdx.x;        // 0 .. 7
    int slice = blockIdx.y;        // 0 .. 255

    int b  = pg / (PP / PTS_PER_BLOCK);   // 4 point-groups per batch
    int p0 = pg * PTS_PER_BLOCK + tid;

    f2 px[4], py[4], pz[4], pp[4], m[4];
    int pidx[8];
#pragma unroll
    for (int k = 0; k < 4; ++k) {
        int pa = p0 + (2*k)   * 256;
        int pb = p0 + (2*k+1) * 256;
        pidx[2*k] = pa; pidx[2*k+1] = pb;
        px[k] = (f2){pts[pa*3+0], pts[pb*3+0]};
        py[k] = (f2){pts[pa*3+1], pts[pb*3+1]};
        pz[k] = (f2){pts[pa*3+2], pts[pb*3+2]};
        pp[k] = vfma(px[k], px[k], vfma(py[k], py[k], pz[k] * pz[k]));
        m[k] = bc(__uint_as_float(0x7F800000u));
    }

    int t0 = b * FF + slice * CHUNK_T;
    const float4* fb = fa + (size_t)t0 * FAST_F4;

    for (int t = 0; t < CHUNK_T; ++t) {
        float4 F0 = fb[t*FAST_F4+0];
        float4 F1 = fb[t*FAST_F4+1];
        float4 F2 = fb[t*FAST_F4+2];
        float4 F3 = fb[t*FAST_F4+3];
        float4 F4 = fb[t*FAST_F4+4];
        float4 F5 = fb[t*FAST_F4+5];
#pragma unroll
        for (int k = 0; k < 4; ++k)
            m[k] = vmin2(m[k], fast_d2_pk(px[k], py[k], pz[k], pp[k],
                                          F0, F1, F2, F3, F4, F5));
    }

    // Phase B: bit-exact eval for flagged slivers in this half-word chunk
    unsigned long long bits =
        (mask[t0 >> 6] >> (t0 & 63)) & 0xFFFFFFFFull;
    while (bits) {
        int bit = __builtin_ctzll(bits);
        bits &= bits - 1;
        const float4* sb = sa + (size_t)(t0 + bit) * SLOW_F4;
        float4 S0 = sb[0], S1 = sb[1], S2 = sb[2], S3 = sb[3], S4 = sb[4];
#pragma unroll
        for (int k = 0; k < 4; ++k) {
            m[k].x = fminf(m[k].x, tri_d2(px[k].x, py[k].x, pz[k].x, S0, S1, S2, S3, S4));
            m[k].y = fminf(m[k].y, tri_d2(px[k].y, py[k].y, pz[k].y, S0, S1, S2, S3, S4));
        }
    }

    // clamp (monotone) then float-as-uint atomicMin (valid: values >= 0)
#pragma unroll
    for (int k = 0; k < 4; ++k) {
        atomicMin(&minD[pidx[2*k]],   __float_as_uint(fmaxf(m[k].x, 0.0f)));
        atomicMin(&minD[pidx[2*k+1]], __float_as_uint(fmaxf(m[k].y, 0.0f)));
    }
}

// ---------------------------------------------------------------------------
// Kernel 3: per-batch reduction (2 blocks), shuffle + LDS, atomicAdd into out
// (out zeroed by precompute_kernel earlier in the stream).
// ---------------------------------------------------------------------------
__global__ __launch_bounds__(256) void reduce_kernel(
    const unsigned int* __restrict__ minD, const float* __restrict__ verts,
    float* __restrict__ out)
{
    int b = blockIdx.x;
    int tid = threadIdx.x;

    float s = 0.0f;
    for (int i = tid; i < PP; i += 256)
        s += __uint_as_float(minD[b * PP + i]);

    float ymin = 3.4e38f, ymax = -3.4e38f;
    for (int i = tid; i < VV; i += 256) {
        float y = verts[((size_t)b * VV + i) * 3 + 1];
        ymin = fminf(ymin, y); ymax = fmaxf(ymax, y);
    }

    for (int off = 32; off > 0; off >>= 1) {
        s += __shfl_down(s, off);
        ymin = fminf(ymin, __shfl_down(ymin, off));
        ymax = fmaxf(ymax, __shfl_down(ymax, off));
    }

    __shared__ float shs[4], shmn[4], shmx[4];
    if ((tid & 63) == 0) {
        int w = tid >> 6;
        shs[w] = s; shmn[w] = ymin; shmx[w] = ymax;
    }
    __syncthreads();
    if (tid == 0) {
        float tot = shs[0], mn = shmn[0], mx = shmx[0];
        for (int w = 1; w < 4; ++w) {
            tot += shs[w];
            mn = fminf(mn, shmn[w]);
            mx = fmaxf(mx, shmx[w]);
        }
        atomicAdd(out, 0.5f * sqrtf(tot) / (mx - mn));  // mean over B=2
    }
}

// ---------------------------------------------------------------------------
extern "C" void kernel_launch(void* const* d_in, const int* in_sizes, int n_in,
                              void* d_out, int out_size, void* d_ws, size_t ws_size,
                              hipStream_t stream) {
    const float* pts   = (const float*)d_in[0];   // [B,P,3]
    const float* verts = (const float*)d_in[1];   // [B,V,3]
    const int*   faces = (const int*)d_in[2];     // [B,F,3]
    float* out = (float*)d_out;

    char* w = (char*)d_ws;
    float4* fastrec = (float4*)w;                                   // 1.5 MB
    w += (size_t)BB * FF * FAST_F4 * sizeof(float4);
    float4* slowrec = (float4*)w;                                   // 1.25 MB
    w += (size_t)BB * FF * SLOW_F4 * sizeof(float4);
    unsigned long long* mask = (unsigned long long*)w;              // 2 KB
    w += (size_t)(BB * FF / 64) * sizeof(unsigned long long);
    unsigned int* minD = (unsigned int*)w;                          // 64 KB

    precompute_kernel<<<(BB * FF + 255) / 256, 256, 0, stream>>>(
        verts, faces, fastrec, slowrec, mask, minD, out);

    dim3 grid(BB * PP / PTS_PER_BLOCK, NSLICES);
    dist_kernel<<<grid, 256, 0, stream>>>(pts, fastrec, slowrec, mask, minD);

    reduce_kernel<<<BB, 256, 0, stream>>>(minD, verts, out);
}

// Round 8
// 208.841 us; speedup vs baseline: 2.8175x; 1.0391x over previous
//
#include <hip/hip_runtime.h>

#define EPSF 1e-12f
constexpr int BB = 2;
constexpr int PP = 8192;
constexpr int VV = 4098;
constexpr int FF = 8192;

constexpr int SLOW_F4 = 5;               // verbatim record: 5 x float4
constexpr int NCONST = 24;               // fast consts per triangle
constexpr int PTS_PER_BLOCK = 1024;      // 4 points/thread x 256 threads
constexpr int NSLICES = 256;
constexpr int CHUNK_T = FF / NSLICES;    // 32 triangles/block (even, half mask word)

typedef float f2 __attribute__((ext_vector_type(2)));

__device__ __forceinline__ f2 vfma(f2 a, f2 b, f2 c) {
#if __has_builtin(__builtin_elementwise_fma)
    return __builtin_elementwise_fma(a, b, c);
#else
    return (f2){fmaf(a.x, b.x, c.x), fmaf(a.y, b.y, c.y)};
#endif
}
__device__ __forceinline__ f2 vmin2(f2 a, f2 b) { return __builtin_elementwise_min(a, b); }
__device__ __forceinline__ f2 vmax2(f2 a, f2 b) { return __builtin_elementwise_max(a, b); }
__device__ __forceinline__ f2 bc(float s) { return (f2){s, s}; }

// monotone float<->uint for atomicMin/Max on y-extent
__device__ __forceinline__ unsigned int fkey(float f) {
    unsigned int u = __float_as_uint(f);
    return (u >> 31) ? ~u : (u | 0x80000000u);
}
__device__ __forceinline__ float funkey(unsigned int k) {
    unsigned int u = (k >> 31) ? (k ^ 0x80000000u) : ~k;
    return __uint_as_float(u);
}

// ---------------------------------------------------------------------------
// Kernel 1: paired fast records + slow records + sliver bitmask + inits.
// Fast consts per triangle (c index): 0-2 ab, 3 ka1, 4-6 ac, 7 ka2, 8-10 n,
// 11 kan*, 12-14 a, 15 aa*, 16 ab2, 17 ac2, 18 abac, 19 bc2,
// 20 1/ab2, 21 1/ac2, 22 1/bc2, 23 1/nn.
// Stored interleaved per triangle-PAIR: pr[(idx>>1)*48 + 2*c + (idx&1)], so
// the dist kernel loads each constant as an f2 = (tri_even, tri_odd) pair
// (wave-uniform -> SGPR pair, used directly by v_pk_* ops).
// Sliver poisoning: kan*=aa*=+inf => all fast candidates +inf for that half.
// ---------------------------------------------------------------------------
__global__ __launch_bounds__(256) void precompute_kernel(
    const float* __restrict__ verts, const int* __restrict__ faces,
    float* __restrict__ pairrec, float4* __restrict__ slowrec,
    unsigned long long* __restrict__ mask, unsigned int* __restrict__ minD,
    float* __restrict__ sums, unsigned int* __restrict__ ykmin,
    unsigned int* __restrict__ ykmax)
{
    int idx = blockIdx.x * 256 + threadIdx.x;   // grid exactly covers BB*FF
    if (idx < BB) { sums[idx] = 0.0f; ykmin[idx] = 0xFFFFFFFFu; ykmax[idx] = 0u; }
    if (idx < BB * PP) minD[idx] = 0x7F800000u; // +inf
    if (idx >= BB * FF) return;

    int b = idx / FF;
    const float* vb = verts + (size_t)b * VV * 3;
    int i0 = faces[idx * 3 + 0];
    int i1 = faces[idx * 3 + 1];
    int i2 = faces[idx * 3 + 2];

    float ax = vb[i0*3+0], ay = vb[i0*3+1], az = vb[i0*3+2];
    float bx = vb[i1*3+0], by = vb[i1*3+1], bz = vb[i1*3+2];
    float cx = vb[i2*3+0], cy = vb[i2*3+1], cz = vb[i2*3+2];

    // plain fp32 subs: bit-match numpy (shared by both records)
    float abx = bx-ax, aby = by-ay, abz = bz-az;
    float acx = cx-ax, acy = cy-ay, acz = cz-az;
    float bcx = cx-bx, bcy = cy-by, bcz = cz-bz;

    {   // slow record (read only for flagged tris)
        float4* t = slowrec + (size_t)idx * SLOW_F4;
        t[0] = make_float4(ax, ay, az, abx);
        t[1] = make_float4(bx, by, bz, aby);
        t[2] = make_float4(cx, cy, cz, abz);
        t[3] = make_float4(acx, acy, acz, bcx);
        t[4] = make_float4(bcy, bcz, 0.0f, 0.0f);
    }

    float nx = aby*acz - abz*acy;
    float ny = abz*acx - abx*acz;
    float nz = abx*acy - aby*acx;

    float ka1  = abx*ax + aby*ay + abz*az;
    float ka2  = acx*ax + acy*ay + acz*az;
    float kan  = nx*ax + ny*ay + nz*az;
    float aa   = ax*ax + ay*ay + az*az;
    float abac = abx*acx + aby*acy + abz*acz;

    float ab2 = abx*abx + aby*aby + abz*abz;
    float ac2 = acx*acx + acy*acy + acz*acz;
    float bc2 = bcx*bcx + bcy*bcy + bcz*bcz;
    float nn  = nx*nx + ny*ny + nz*nz;

    float inv_ab2 = 1.0f / fmaxf(ab2, EPSF);
    float inv_ac2 = 1.0f / fmaxf(ac2, EPSF);
    float inv_bc2 = 1.0f / fmaxf(bc2, EPSF);
    float inv_nn  = 1.0f / fmaxf(nn,  EPSF);

    // sliver/degenerate classifier: sin^2(angle at a) <= 3e-2 or tiny edges
    bool slowtri = !((nn > 0.03f * (ab2 * ac2)) &&
                     (ab2 > 1e-4f) && (ac2 > 1e-4f) && (bc2 > 1e-4f));

    unsigned long long mb = __ballot(slowtri);
    if ((threadIdx.x & 63) == 0) mask[idx >> 6] = mb;

    float INF = __uint_as_float(0x7F800000u);
    float cvals[NCONST] = {
        abx, aby, abz, ka1,
        acx, acy, acz, ka2,
        nx,  ny,  nz,  slowtri ? INF : kan,
        ax,  ay,  az,  slowtri ? INF : aa,
        ab2, ac2, abac, bc2,
        inv_ab2, inv_ac2, inv_bc2, inv_nn
    };
    float* pr = pairrec + (size_t)(idx >> 1) * (2 * NCONST) + (idx & 1);
#pragma unroll
    for (int c = 0; c < NCONST; ++c) pr[2*c] = cvals[c];
}

// ---------------------------------------------------------------------------
// Verbatim fp32 port (bit-exact vs numpy) — slivers only. Proven in R3.
// ---------------------------------------------------------------------------
__device__ __forceinline__ float tri_d2(
    float px, float py, float pz,
    float4 R0, float4 R1, float4 R2, float4 R3, float4 R4)
{
#pragma clang fp contract(off)
    float ax = R0.x, ay = R0.y, az = R0.z;
    float bx = R1.x, by = R1.y, bz = R1.z;
    float cx = R2.x, cy = R2.y, cz = R2.z;
    float abx = R0.w, aby = R1.w, abz = R2.w;
    float acx = R3.x, acy = R3.y, acz = R3.z;
    float bcx = R3.w, bcy = R4.x, bcz = R4.y;

    float apx = px - ax, apy = py - ay, apz = pz - az;
    float d1 = (abx*apx + aby*apy) + abz*apz;
    float d2 = (acx*apx + acy*apy) + acz*apz;
    float bpx = px - bx, bpy = py - by, bpz = pz - bz;
    float d3 = (abx*bpx + aby*bpy) + abz*bpz;
    float d4 = (acx*bpx + acy*bpy) + acz*bpz;
    float cqx = px - cx, cqy = py - cy, cqz = pz - cz;
    float d5 = (abx*cqx + aby*cqy) + abz*cqz;
    float d6 = (acx*cqx + acy*cqy) + acz*cqz;

    float va = d3*d6 - d5*d4;
    float vb = d5*d2 - d1*d6;
    float vc = d1*d4 - d3*d2;
    float u43 = d4 - d3;
    float u56 = d5 - d6;

    bool c1 = (d1 <= 0.0f) && (d2 <= 0.0f);
    bool c2 = (d3 >= 0.0f) && (d4 <= d3);
    bool c3 = (d6 >= 0.0f) && (d5 <= d6);
    bool c4 = (vc <= 0.0f) && (d1 >= 0.0f) && (d3 <= 0.0f);
    bool c5 = (vb <= 0.0f) && (d2 >= 0.0f) && (d6 <= 0.0f);
    bool c6 = (va <= 0.0f) && (u43 >= 0.0f) && (u56 >= 0.0f);

    int reg = c1 ? 0 : (c2 ? 1 : (c3 ? 2 : (c4 ? 3 : (c5 ? 4 : (c6 ? 5 : 6)))));

    float denom = fmaxf((va + vb) + vc, EPSF);
    float den1 = (reg == 3) ? fmaxf(d1 - d3, EPSF)
               : (reg == 5) ? fmaxf(u43 + u56, EPSF)
               : (reg == 6) ? denom : 1.0f;
    float num1 = (reg == 3) ? d1
               : (reg == 5) ? u43
               : (reg == 6) ? vb : 0.0f;
    float den2 = (reg == 4) ? fmaxf(d2 - d6, EPSF)
               : (reg == 6) ? denom : 1.0f;
    float num2 = (reg == 4) ? d2
               : (reg == 6) ? vc : 0.0f;
    float s = num1 / den1;
    float t = num2 / den2;

    bool useB = (reg == 1) || (reg == 5);
    bool useC = (reg == 2);
    float basex = useB ? bx : (useC ? cx : ax);
    float basey = useB ? by : (useC ? cy : ay);
    float basez = useB ? bz : (useC ? cz : az);
    bool e1bc = (reg == 5);
    float e1x = e1bc ? bcx : abx;
    float e1y = e1bc ? bcy : aby;
    float e1z = e1bc ? bcz : abz;

    float cpx = (basex + e1x*s) + acx*t;
    float cpy = (basey + e1y*s) + acy*t;
    float cpz = (basez + e1z*s) + acz*t;
    float rx = px - cpx, ry = py - cpy, rz = pz - cpz;
    return (rx*rx + ry*ry) + rz*rz;
}

// ---------------------------------------------------------------------------
// Kernel 2: 4 points/thread (replicated to both f2 halves, hoisted), TWO
// TRIANGLES per packed op. Constants are (tri0,tri1) f2 pairs from the
// pre-interleaved record — wave-uniform, no per-iteration broadcast movs.
// ---------------------------------------------------------------------------
__global__ __launch_bounds__(256) void dist_kernel(
    const float* __restrict__ pts, const f2* __restrict__ pair,
    const float4* __restrict__ sa, const unsigned long long* __restrict__ mask,
    unsigned int* __restrict__ minD)
{
    const float INF = __uint_as_float(0x7F800000u);
    int tid   = threadIdx.x;
    int pg    = blockIdx.x;        // 0 .. 15
    int slice = blockIdx.y;        // 0 .. 255

    int b  = pg / (PP / PTS_PER_BLOCK);   // 8 point-groups per batch
    int p0 = pg * PTS_PER_BLOCK + tid;

    float PX[4], PY[4], PZ[4];
    f2 X[4], Y[4], Z[4], W[4], m[4];
#pragma unroll
    for (int k = 0; k < 4; ++k) {
        int p = p0 + k * 256;
        PX[k] = pts[p*3+0]; PY[k] = pts[p*3+1]; PZ[k] = pts[p*3+2];
        X[k] = bc(PX[k]); Y[k] = bc(PY[k]); Z[k] = bc(PZ[k]);
        W[k] = vfma(X[k], X[k], vfma(Y[k], Y[k], Z[k] * Z[k]));
        m[k] = bc(INF);
    }

    int t0 = b * FF + slice * CHUNK_T;
    const f2* cb = pair + (size_t)(t0 >> 1) * NCONST;

    for (int tp = 0; tp < CHUNK_T / 2; ++tp) {
        const f2* c = cb + tp * NCONST;
        f2 abx=c[0], aby=c[1], abz=c[2], ka1=c[3];
        f2 acx=c[4], acy=c[5], acz=c[6], ka2=c[7];
        f2 nx=c[8],  ny=c[9],  nz=c[10], kan=c[11];
        f2 ax=c[12], ay=c[13], az=c[14], aa=c[15];
        f2 ab2=c[16], ac2=c[17], abac=c[18], bc2=c[19];
        f2 iab2=c[20], iac2=c[21], ibc2=c[22], inn=c[23];

#pragma unroll
        for (int k = 0; k < 4; ++k) {
            f2 sab = vfma(abx, X[k], vfma(aby, Y[k], abz * Z[k]));
            f2 sac = vfma(acx, X[k], vfma(acy, Y[k], acz * Z[k]));
            f2 sn  = vfma(nx,  X[k], vfma(ny,  Y[k], nz  * Z[k]));
            f2 adp = vfma(ax,  X[k], vfma(ay,  Y[k], az  * Z[k]));

            f2 d1 = sab - ka1, d2 = sac - ka2;
            f2 d3 = d1 - ab2, d4 = d2 - abac;
            f2 d5 = d1 - abac, d6 = d2 - ac2;
            f2 tpn = sn - kan;                     // -inf if poisoned

            f2 ap2 = vfma(bc(-2.0f), adp, W[k]) + aa;   // +inf if poisoned
            f2 bp2 = vfma(bc(-2.0f), d1, ap2) + ab2;

            f2 sA = vmin2(vmax2(d1 * iab2, bc(0.0f)), bc(1.0f));   // edge AB
            f2 dAB = vfma(-sA, vfma(-sA, ab2, d1 + d1), ap2);
            f2 sC = vmin2(vmax2(d2 * iac2, bc(0.0f)), bc(1.0f));   // edge AC
            f2 dAC = vfma(-sC, vfma(-sC, ac2, d2 + d2), ap2);
            f2 u43 = d4 - d3;
            f2 sB = vmin2(vmax2(u43 * ibc2, bc(0.0f)), bc(1.0f));  // edge BC
            f2 dBC = vfma(-sB, vfma(-sB, bc2, u43 + u43), bp2);

            f2 va = vfma(d3, d6, -(d5 * d4));
            f2 vb = vfma(d5, d2, -(d1 * d6));
            f2 vc = vfma(d1, d4, -(d3 * d2));
            f2 mv = vmin2(vmin2(va, vb), vc);
            f2 dIN = (tpn * tpn) * inn;            // +inf if poisoned

            f2 dI;
            dI.x = (mv.x >= 0.0f) ? dIN.x : INF;
            dI.y = (mv.y >= 0.0f) ? dIN.y : INF;

            m[k] = vmin2(m[k], vmin2(vmin2(dAB, dAC), vmin2(dBC, dI)));
        }
    }

    // Phase B: bit-exact eval for flagged slivers in this half-word chunk
    unsigned long long bits =
        (mask[t0 >> 6] >> (t0 & 63)) & 0xFFFFFFFFull;
    while (bits) {
        int bit = __builtin_ctzll(bits);
        bits &= bits - 1;
        const float4* sb = sa + (size_t)(t0 + bit) * SLOW_F4;
        float4 S0 = sb[0], S1 = sb[1], S2 = sb[2], S3 = sb[3], S4 = sb[4];
#pragma unroll
        for (int k = 0; k < 4; ++k)
            m[k].x = fminf(m[k].x, tri_d2(PX[k], PY[k], PZ[k], S0, S1, S2, S3, S4));
    }

    // fold tri-pair halves, clamp (monotone), float-as-uint atomicMin
#pragma unroll
    for (int k = 0; k < 4; ++k) {
        float r = fminf(m[k].x, m[k].y);
        atomicMin(&minD[p0 + k*256], __float_as_uint(fmaxf(r, 0.0f)));
    }
}

// ---------------------------------------------------------------------------
// Kernel 3a: partial reductions, 8 blocks per batch.
// ---------------------------------------------------------------------------
__global__ __launch_bounds__(256) void reduce1_kernel(
    const unsigned int* __restrict__ minD, const float* __restrict__ verts,
    float* __restrict__ sums, unsigned int* __restrict__ ykmin,
    unsigned int* __restrict__ ykmax)
{
    int blk = blockIdx.x;          // 0 .. 15
    int b = blk >> 3, part = blk & 7;
    int tid = threadIdx.x;

    float s = 0.0f;
    int i0 = part * (PP / 8), i1 = i0 + (PP / 8);
    for (int i = i0 + tid; i < i1; i += 256)
        s += __uint_as_float(minD[b * PP + i]);

    float ymin = 3.4e38f, ymax = -3.4e38f;
    int v0 = part * 513, v1 = min(v0 + 513, VV);
    for (int i = v0 + tid; i < v1; i += 256) {
        float y = verts[((size_t)b * VV + i) * 3 + 1];
        ymin = fminf(ymin, y); ymax = fmaxf(ymax, y);
    }

    for (int off = 32; off > 0; off >>= 1) {
        s += __shfl_down(s, off);
        ymin = fminf(ymin, __shfl_down(ymin, off));
        ymax = fmaxf(ymax, __shfl_down(ymax, off));
    }

    __shared__ float shs[4], shmn[4], shmx[4];
    if ((tid & 63) == 0) {
        int w = tid >> 6;
        shs[w] = s; shmn[w] = ymin; shmx[w] = ymax;
    }
    __syncthreads();
    if (tid == 0) {
        float tot = shs[0], mn = shmn[0], mx = shmx[0];
        for (int w = 1; w < 4; ++w) {
            tot += shs[w];
            mn = fminf(mn, shmn[w]);
            mx = fmaxf(mx, shmx[w]);
        }
        atomicAdd(&sums[b], tot);
        atomicMin(&ykmin[b], fkey(mn));
        atomicMax(&ykmax[b], fkey(mx));
    }
}

// ---------------------------------------------------------------------------
// Kernel 3b: finish — combine per-batch partials into the scalar loss.
// ---------------------------------------------------------------------------
__global__ __launch_bounds__(64) void reduce2_kernel(
    const float* __restrict__ sums, const unsigned int* __restrict__ ykmin,
    const unsigned int* __restrict__ ykmax, float* __restrict__ out)
{
    if (threadIdx.x == 0) {
        float r = 0.0f;
        for (int b = 0; b < BB; ++b) {
            float h = funkey(ykmax[b]) - funkey(ykmin[b]);
            r += sqrtf(sums[b]) / h;
        }
        out[0] = r * 0.5f;   // mean over B=2, LOSS_WEIGHT=1
    }
}

// ---------------------------------------------------------------------------
extern "C" void kernel_launch(void* const* d_in, const int* in_sizes, int n_in,
                              void* d_out, int out_size, void* d_ws, size_t ws_size,
                              hipStream_t stream) {
    const float* pts   = (const float*)d_in[0];   // [B,P,3]
    const float* verts = (const float*)d_in[1];   // [B,V,3]
    const int*   faces = (const int*)d_in[2];     // [B,F,3]
    float* out = (float*)d_out;

    char* w = (char*)d_ws;
    float* pairrec = (float*)w;                                     // 3.0 MB
    w += (size_t)(BB * FF / 2) * (2 * NCONST) * sizeof(float);
    float4* slowrec = (float4*)w;                                   // 1.25 MB
    w += (size_t)BB * FF * SLOW_F4 * sizeof(float4);
    unsigned long long* mask = (unsigned long long*)w;              // 2 KB
    w += (size_t)(BB * FF / 64) * sizeof(unsigned long long);
    unsigned int* minD = (unsigned int*)w;                          // 64 KB
    w += (size_t)BB * PP * sizeof(unsigned int);
    float* sums = (float*)w;          w += BB * sizeof(float);
    unsigned int* ykmin = (unsigned int*)w; w += BB * sizeof(unsigned int);
    unsigned int* ykmax = (unsigned int*)w;

    precompute_kernel<<<(BB * FF + 255) / 256, 256, 0, stream>>>(
        verts, faces, pairrec, slowrec, mask, minD, sums, ykmin, ykmax);

    dim3 grid(BB * PP / PTS_PER_BLOCK, NSLICES);
    dist_kernel<<<grid, 256, 0, stream>>>(pts, (const f2*)pairrec, slowrec, mask, minD);

    reduce1_kernel<<<16, 256, 0, stream>>>(minD, verts, sums, ykmin, ykmax);
    reduce2_kernel<<<1, 64, 0, stream>>>(sums, ykmin, ykmax, out);
}